// Round 5
// baseline (725.963 us; speedup 1.0000x reference)
//
#include <hip/hip_runtime.h>

#define NE 524288
#define NN 32768
#define NB 1024

#define F4(p) (*(const float4*)(p))

__device__ __forceinline__ float sigmoidf_(float v) { return 1.f / (1.f + expf(-v)); }

__device__ __forceinline__ void ld32(float* xr, const float* p) {
#pragma unroll
  for (int i = 0; i < 32; i += 4) {
    float4 v = F4(&p[i]);
    xr[i] = v.x; xr[i+1] = v.y; xr[i+2] = v.z; xr[i+3] = v.w;
  }
}

__device__ __forceinline__ float dot32r(const float* __restrict__ w, const float* xr) {
  float s = 0.f;
#pragma unroll
  for (int i = 0; i < 32; i += 4) {
    float4 ww = F4(&w[i]);
    s = fmaf(xr[i],   ww.x, s);
    s = fmaf(xr[i+1], ww.y, s);
    s = fmaf(xr[i+2], ww.z, s);
    s = fmaf(xr[i+3], ww.w, s);
  }
  return s;
}

// ---------------- embedding ----------------
__global__ __launch_bounds__(128) void embed_kernel(
    const float* __restrict__ xa, const float* __restrict__ W,
    const float* __restrict__ b, float* __restrict__ x)
{
  __shared__ float a[64];
  const int n = blockIdx.x, t = threadIdx.x;
  if (t < 64) a[t] = xa[n*64 + t];
  __syncthreads();
  float s = b[t];
#pragma unroll 8
  for (int f = 0; f < 64; ++f) s = fmaf(a[f], W[f*128 + t], s);
  x[n*128 + t] = s;
}

// ---------------- CSR build ----------------
__global__ __launch_bounds__(256) void hist_kernel(const int* __restrict__ ei, int* __restrict__ cnt) {
  const int e = blockIdx.x*256 + threadIdx.x;
  atomicAdd(&cnt[ei[NE + e]], 1);
}

__global__ __launch_bounds__(1024) void scan_kernel(
    const int* __restrict__ cnt, int* __restrict__ off, int* __restrict__ cur)
{
  __shared__ int wsum[16];
  const int t = threadIdx.x;
  int local[32];
  const int base = t*32;
  int s = 0;
#pragma unroll
  for (int i = 0; i < 32; ++i) { local[i] = cnt[base+i]; s += local[i]; }
  int pre = s;
  const int lane = t & 63;
#pragma unroll
  for (int o = 1; o < 64; o <<= 1) { int v = __shfl_up(pre, o); if (lane >= o) pre += v; }
  if (lane == 63) wsum[t >> 6] = pre;
  __syncthreads();
  if (t == 0) { int a = 0; for (int w = 0; w < 16; ++w) { int v = wsum[w]; wsum[w] = a; a += v; } }
  __syncthreads();
  int excl = wsum[t >> 6] + pre - s;
#pragma unroll
  for (int i = 0; i < 32; ++i) { off[base+i] = excl; cur[base+i] = excl; excl += local[i]; }
  if (t == 1023) off[NN] = excl;
}

__global__ __launch_bounds__(256) void scatter_kernel(
    const float* __restrict__ pos, const int* __restrict__ ei,
    int* __restrict__ cur, int* __restrict__ csr_src, float* __restrict__ csr_df)
{
  const int e = blockIdx.x*256 + threadIdx.x;
  const int s = ei[e];
  const int d = ei[NE + e];
  float dx = pos[d*3+0] - pos[s*3+0];
  float dy = pos[d*3+1] - pos[s*3+1];
  float dz = pos[d*3+2] - pos[s*3+2];
  float dist = sqrtf(dx*dx + dy*dy + dz*dz + 1e-12f);
  const int slot = atomicAdd(&cur[d], 1);
  csr_src[slot] = s;
  csr_df[slot*3+0] = dist;
  csr_df[slot*3+1] = 1.f/(1.f + dist);
  csr_df[slot*3+2] = expf(-dist);
}

// ---------------- 32x32 tile transpose ----------------
__global__ __launch_bounds__(256) void transpose_kernel(
    const float* __restrict__ in, float* __restrict__ out, int rows, int cols)
{
  __shared__ float tile[32][33];
  const int c0 = blockIdx.x*32, r0 = blockIdx.y*32;
  const int t = threadIdx.x;
  const int tr = t >> 5, tc = t & 31;
  for (int i = tr; i < 32; i += 8)
    tile[i][tc] = in[(r0+i)*cols + (c0+tc)];
  __syncthreads();
  for (int i = tr; i < 32; i += 8)
    out[(c0+i)*rows + (r0+tc)] = tile[tc][i];
}

// FMA step macros (fully unrolled 4x4 register tiles)
#define PQ_STEP(aV, pV, qV) do { \
  const float av_[4] = {(aV).x,(aV).y,(aV).z,(aV).w}; \
  const float pv_[4] = {(pV).x,(pV).y,(pV).z,(pV).w}; \
  const float qv_[4] = {(qV).x,(qV).y,(qV).z,(qV).w}; \
  _Pragma("unroll") for (int j_ = 0; j_ < 4; ++j_) \
    _Pragma("unroll") for (int i_ = 0; i_ < 4; ++i_) { \
      pa[j_][i_] = fmaf(av_[j_], pv_[i_], pa[j_][i_]); \
      qa[j_][i_] = fmaf(av_[j_], qv_[i_], qa[j_][i_]); } \
} while(0)

#define GE_STEP(aV, wV) do { \
  const float av_[4] = {(aV).x,(aV).y,(aV).z,(aV).w}; \
  const float wv_[4] = {(wV).x,(wV).y,(wV).z,(wV).w}; \
  _Pragma("unroll") for (int j_ = 0; j_ < 4; ++j_) \
    _Pragma("unroll") for (int i_ = 0; i_ < 4; ++i_) \
      acc[j_][i_] = fmaf(av_[j_], wv_[i_], acc[j_][i_]); \
} while(0)

#define QKV_STEP(aV, w0V, w1V, w2V) do { \
  const float av_[4] = {(aV).x,(aV).y,(aV).z,(aV).w}; \
  const float w0_[4] = {(w0V).x,(w0V).y,(w0V).z,(w0V).w}; \
  const float w1_[4] = {(w1V).x,(w1V).y,(w1V).z,(w1V).w}; \
  const float w2_[4] = {(w2V).x,(w2V).y,(w2V).z,(w2V).w}; \
  _Pragma("unroll") for (int j_ = 0; j_ < 4; ++j_) \
    _Pragma("unroll") for (int i_ = 0; i_ < 4; ++i_) { \
      aq[j_][i_] = fmaf(av_[j_], w0_[i_], aq[j_][i_]); \
      ak[j_][i_] = fmaf(av_[j_], w1_[i_], ak[j_][i_]); \
      av2[j_][i_] = fmaf(av_[j_], w2_[i_], av2[j_][i_]); } \
} while(0)

// ---------------- P = x@W1a + b1 ; Q = x@W1b  (depth-2 SW pipeline) ----------------
__global__ __launch_bounds__(256, 4) void pq_kernel(
    const float* __restrict__ x, const float* __restrict__ W1,
    const float* __restrict__ b1, float* __restrict__ P, float* __restrict__ Q)
{
  __shared__ float xT[128*33];
  const int tid = threadIdx.x;
  const int n0 = blockIdx.x * 32;
  for (int idx = tid; idx < 1024; idx += 256) {
    const int n = idx >> 5, c4 = idx & 31;
    float4 v = F4(&x[(n0+n)*128 + c4*4]);
    xT[(c4*4+0)*33 + n] = v.x;
    xT[(c4*4+1)*33 + n] = v.y;
    xT[(c4*4+2)*33 + n] = v.z;
    xT[(c4*4+3)*33 + n] = v.w;
  }
  __syncthreads();

  const int eg = tid & 7, cg = tid >> 3;
  const int e0 = eg*4, c0 = cg*4;
  const float* __restrict__ W1b = W1 + 128*128;
  const float* xp = &xT[e0];

  float pa[4][4], qa[4][4];
#pragma unroll
  for (int j = 0; j < 4; ++j)
#pragma unroll
    for (int i = 0; i < 4; ++i) { pa[j][i] = 0.f; qa[j][i] = 0.f; }

  float4 aA = F4(xp);
  float4 pA = F4(&W1[c0]);
  float4 qA = F4(&W1b[c0]);
  float4 aB = F4(xp + 33);
  float4 pB = F4(&W1[128 + c0]);
  float4 qB = F4(&W1b[128 + c0]);
  for (int k = 0; k < 126; k += 2) {
    float4 aC = F4(xp + (k+2)*33);
    float4 pC = F4(&W1[(k+2)*128 + c0]);
    float4 qC = F4(&W1b[(k+2)*128 + c0]);
    PQ_STEP(aA, pA, qA);
    float4 aD = F4(xp + (k+3)*33);
    float4 pD = F4(&W1[(k+3)*128 + c0]);
    float4 qD = F4(&W1b[(k+3)*128 + c0]);
    PQ_STEP(aB, pB, qB);
    aA = aC; pA = pC; qA = qC;
    aB = aD; pB = pD; qB = qD;
  }
  PQ_STEP(aA, pA, qA);
  PQ_STEP(aB, pB, qB);

  const float4 bl = F4(&b1[c0]);
#pragma unroll
  for (int j = 0; j < 4; ++j) {
    const int row = (n0 + e0 + j)*128 + c0;
    *(float4*)&P[row] = make_float4(pa[j][0]+bl.x, pa[j][1]+bl.y, pa[j][2]+bl.z, pa[j][3]+bl.w);
    *(float4*)&Q[row] = make_float4(qa[j][0], qa[j][1], qa[j][2], qa[j][3]);
  }
}

// ---------------- aggregation: P[n] <- mean_e relu(P[n]+Q[src]+df@W1c) ----------------
__global__ __launch_bounds__(256) void agg_kernel(
    float* __restrict__ P, const float* __restrict__ Q,
    const int* __restrict__ csr_off, const int* __restrict__ csr_src,
    const float* __restrict__ csr_df, const float* __restrict__ W1)
{
  const int tid = threadIdx.x;
  const int node = blockIdx.x*4 + (tid >> 6);
  const int lane = tid & 63;
  const int c0 = lane*2;
  const int off0 = csr_off[node], off1 = csr_off[node+1];

  const float* __restrict__ w1c = W1 + 256*128;
  const float w00 = w1c[c0],       w01 = w1c[c0+1];
  const float w10 = w1c[128+c0],   w11 = w1c[128+c0+1];
  const float w20 = w1c[256+c0],   w21 = w1c[256+c0+1];
  const float2 p = *(const float2*)&P[node*128 + c0];

  float a0 = 0.f, a1 = 0.f;
  int e = off0;
  for (; e + 4 <= off1; e += 4) {
#pragma unroll
    for (int j = 0; j < 4; ++j) {
      const int src = csr_src[e+j];
      const float d0 = csr_df[(e+j)*3+0];
      const float d1 = csr_df[(e+j)*3+1];
      const float d2 = csr_df[(e+j)*3+2];
      const float2 q = *(const float2*)&Q[src*128 + c0];
      float h0 = p.x + q.x;
      h0 = fmaf(d0, w00, h0); h0 = fmaf(d1, w10, h0); h0 = fmaf(d2, w20, h0);
      float h1 = p.y + q.y;
      h1 = fmaf(d0, w01, h1); h1 = fmaf(d1, w11, h1); h1 = fmaf(d2, w21, h1);
      a0 += fmaxf(h0, 0.f);
      a1 += fmaxf(h1, 0.f);
    }
  }
  for (; e < off1; ++e) {
    const int src = csr_src[e];
    const float d0 = csr_df[e*3+0];
    const float d1 = csr_df[e*3+1];
    const float d2 = csr_df[e*3+2];
    const float2 q = *(const float2*)&Q[src*128 + c0];
    float h0 = p.x + q.x;
    h0 = fmaf(d0, w00, h0); h0 = fmaf(d1, w10, h0); h0 = fmaf(d2, w20, h0);
    float h1 = p.y + q.y;
    h1 = fmaf(d0, w01, h1); h1 = fmaf(d1, w11, h1); h1 = fmaf(d2, w21, h1);
    a0 += fmaxf(h0, 0.f);
    a1 += fmaxf(h1, 0.f);
  }
  const int deg = off1 - off0;
  const float rc = deg > 0 ? 1.f/(float)deg : 1.f;
  *(float2*)&P[node*128 + c0] = make_float2(a0*rc, a1*rc);
}

// ---------------- x <- LN(A@W2 + (deg>0)*b2 + x)  (depth-2 SW pipeline) ----------------
__global__ __launch_bounds__(256, 4) void gemm_ln_kernel(
    const float* __restrict__ A, const float* __restrict__ W2,
    const float* __restrict__ b2, const int* __restrict__ csr_off,
    const float* __restrict__ g, const float* __restrict__ bb,
    float* __restrict__ x)
{
  __shared__ float smem[128*33];
  const int tid = threadIdx.x;
  const int n0 = blockIdx.x * 32;
  for (int idx = tid; idx < 1024; idx += 256) {
    const int n = idx >> 5, c4 = idx & 31;
    float4 v = F4(&A[(n0+n)*128 + c4*4]);
    smem[(c4*4+0)*33 + n] = v.x;
    smem[(c4*4+1)*33 + n] = v.y;
    smem[(c4*4+2)*33 + n] = v.z;
    smem[(c4*4+3)*33 + n] = v.w;
  }
  __syncthreads();

  const int eg = tid & 7, cg = tid >> 3;
  const int e0 = eg*4, c0 = cg*4;
  const float* xp = &smem[e0];

  float acc[4][4];
#pragma unroll
  for (int j = 0; j < 4; ++j)
#pragma unroll
    for (int i = 0; i < 4; ++i) acc[j][i] = 0.f;

  float4 aA = F4(xp);
  float4 wA = F4(&W2[c0]);
  float4 aB = F4(xp + 33);
  float4 wB = F4(&W2[128 + c0]);
  for (int k = 0; k < 126; k += 2) {
    float4 aC = F4(xp + (k+2)*33);
    float4 wC = F4(&W2[(k+2)*128 + c0]);
    GE_STEP(aA, wA);
    float4 aD = F4(xp + (k+3)*33);
    float4 wD = F4(&W2[(k+3)*128 + c0]);
    GE_STEP(aB, wB);
    aA = aC; wA = wC;
    aB = aD; wB = wD;
  }
  GE_STEP(aA, wA);
  GE_STEP(aB, wB);
  __syncthreads();

  const float4 bl = F4(&b2[c0]);
#pragma unroll
  for (int j = 0; j < 4; ++j) {
    const int n = n0 + e0 + j;
    const float s = (csr_off[n+1] > csr_off[n]) ? 1.f : 0.f;
    const float4 x0 = F4(&x[n*128 + c0]);
    float4 o;
    o.x = acc[j][0] + s*bl.x + x0.x;
    o.y = acc[j][1] + s*bl.y + x0.y;
    o.z = acc[j][2] + s*bl.z + x0.z;
    o.w = acc[j][3] + s*bl.w + x0.w;
    *(float4*)&smem[(e0+j)*132 + c0] = o;
  }
  __syncthreads();

  const int a = tid >> 3, q8 = tid & 7;
  const float* row = &smem[a*132 + q8*16];
  float s1 = 0.f, s2 = 0.f;
#pragma unroll
  for (int i = 0; i < 16; ++i) { const float v = row[i]; s1 += v; s2 = fmaf(v, v, s2); }
  s1 += __shfl_xor(s1, 1); s2 += __shfl_xor(s2, 1);
  s1 += __shfl_xor(s1, 2); s2 += __shfl_xor(s2, 2);
  s1 += __shfl_xor(s1, 4); s2 += __shfl_xor(s2, 4);
  const float mu = s1 * (1.f/128.f);
  const float var = s2 * (1.f/128.f) - mu*mu;
  const float rstd = rsqrtf(var + 1e-5f);
#pragma unroll
  for (int i = 0; i < 16; i += 4) {
    const float4 gg = F4(&g[q8*16 + i]);
    const float4 bv = F4(&bb[q8*16 + i]);
    float4 o;
    o.x = (row[i]   - mu)*rstd*gg.x + bv.x;
    o.y = (row[i+1] - mu)*rstd*gg.y + bv.y;
    o.z = (row[i+2] - mu)*rstd*gg.z + bv.z;
    o.w = (row[i+3] - mu)*rstd*gg.w + bv.w;
    *(float4*)&x[(n0+a)*128 + q8*16 + i] = o;
  }
}

// ---------------- qkv = x @ winT + bin  (fused 3-chunk, depth-2 pipeline) ----------------
__global__ __launch_bounds__(256, 4) void qkv_kernel(
    const float* __restrict__ x, const float* __restrict__ winT,
    const float* __restrict__ bin,
    float* __restrict__ dq, float* __restrict__ dk, float* __restrict__ dv)
{
  __shared__ float xT[128*33];
  const int tid = threadIdx.x;
  const int n0 = blockIdx.x * 32;
  for (int idx = tid; idx < 1024; idx += 256) {
    const int n = idx >> 5, c4 = idx & 31;
    float4 v = F4(&x[(n0+n)*128 + c4*4]);
    xT[(c4*4+0)*33 + n] = v.x;
    xT[(c4*4+1)*33 + n] = v.y;
    xT[(c4*4+2)*33 + n] = v.z;
    xT[(c4*4+3)*33 + n] = v.w;
  }
  __syncthreads();

  const int eg = tid & 7, cg = tid >> 3;
  const int e0 = eg*4, c0 = cg*4;
  const float* xp = &xT[e0];

  float aq[4][4], ak[4][4], av2[4][4];
#pragma unroll
  for (int j = 0; j < 4; ++j)
#pragma unroll
    for (int i = 0; i < 4; ++i) { aq[j][i] = 0.f; ak[j][i] = 0.f; av2[j][i] = 0.f; }

  float4 aA  = F4(xp);
  float4 w0A = F4(&winT[c0]);
  float4 w1A = F4(&winT[128 + c0]);
  float4 w2A = F4(&winT[256 + c0]);
  for (int k = 0; k < 127; ++k) {
    const int kn = k + 1;
    float4 aB  = F4(xp + kn*33);
    float4 w0B = F4(&winT[kn*384 + c0]);
    float4 w1B = F4(&winT[kn*384 + 128 + c0]);
    float4 w2B = F4(&winT[kn*384 + 256 + c0]);
    QKV_STEP(aA, w0A, w1A, w2A);
    aA = aB; w0A = w0B; w1A = w1B; w2A = w2B;
  }
  QKV_STEP(aA, w0A, w1A, w2A);

  const float4 bq = F4(&bin[c0]);
  const float4 bk = F4(&bin[128 + c0]);
  const float4 bv = F4(&bin[256 + c0]);
#pragma unroll
  for (int j = 0; j < 4; ++j) {
    const int row = (n0 + e0 + j)*128 + c0;
    *(float4*)&dq[row] = make_float4(aq[j][0]+bq.x, aq[j][1]+bq.y, aq[j][2]+bq.z, aq[j][3]+bq.w);
    *(float4*)&dk[row] = make_float4(ak[j][0]+bk.x, ak[j][1]+bk.y, ak[j][2]+bk.z, ak[j][3]+bk.w);
    *(float4*)&dv[row] = make_float4(av2[j][0]+bv.x, av2[j][1]+bv.y, av2[j][2]+bv.z, av2[j][3]+bv.w);
  }
}

// ---------------- per-molecule attention: O = softmax(qk)v ----------------
__global__ __launch_bounds__(128) void attn_kernel(
    const float* __restrict__ dq, const float* __restrict__ dk,
    const float* __restrict__ dv, float* __restrict__ O)
{
  __shared__ float sk[32*132];
  __shared__ float sv[32*132];
  const int tid = threadIdx.x;
  const int b = blockIdx.x;

  for (int idx = tid; idx < 1024; idx += 128) {
    const int a = idx >> 5, c4 = idx & 31;
    *(float4*)&sk[a*132 + c4*4] = F4(&dk[(b*32+a)*128 + c4*4]);
    *(float4*)&sv[a*132 + c4*4] = F4(&dv[(b*32+a)*128 + c4*4]);
  }
  __syncthreads();

  const int h = tid >> 5, qr = tid & 31;
  float qreg[32];
  ld32(qreg, &dq[(b*32+qr)*128 + h*32]);

  float sc[32];
#pragma unroll
  for (int k = 0; k < 32; ++k)
    sc[k] = dot32r(&sk[k*132 + h*32], qreg) * 0.17677669529663687f;
  float mx = sc[0];
#pragma unroll
  for (int k = 1; k < 32; ++k) mx = fmaxf(mx, sc[k]);
  float se = 0.f;
#pragma unroll
  for (int k = 0; k < 32; ++k) { sc[k] = expf(sc[k] - mx); se += sc[k]; }
  const float inv = 1.f / se;

  __syncthreads();  // done reading sk; reuse as O staging

  float od[32];
#pragma unroll
  for (int i = 0; i < 32; ++i) od[i] = 0.f;
#pragma unroll 4
  for (int k = 0; k < 32; ++k) {
    const float w = sc[k] * inv;
    const float* vr = &sv[k*132 + h*32];
#pragma unroll
    for (int i = 0; i < 32; i += 4) {
      float4 v = F4(&vr[i]);
      od[i]   = fmaf(w, v.x, od[i]);
      od[i+1] = fmaf(w, v.y, od[i+1]);
      od[i+2] = fmaf(w, v.z, od[i+2]);
      od[i+3] = fmaf(w, v.w, od[i+3]);
    }
  }
#pragma unroll
  for (int i = 0; i < 32; i += 4)
    *(float4*)&sk[qr*132 + h*32 + i] = make_float4(od[i], od[i+1], od[i+2], od[i+3]);
  __syncthreads();

  for (int idx = tid; idx < 1024; idx += 128) {
    const int a = idx >> 5, c4 = idx & 31;
    *(float4*)&O[(b*32+a)*128 + c4*4] = F4(&sk[a*132 + c4*4]);
  }
}

// ---------------- attended = O @ woutT + bout, fused pooling + proj ----------------
__global__ __launch_bounds__(256, 4) void attout_pool_kernel(
    const float* __restrict__ O, const float* __restrict__ woutT,
    const float* __restrict__ bout, const float* __restrict__ x,
    const float* __restrict__ pW, const float* __restrict__ pb,
    float* __restrict__ expl, float* __restrict__ lrn)
{
  __shared__ float OT[4224];   // [128][33] stage; aliased as satt [32][132] after GEMM
  __shared__ float sx[4224];   // [32][132]
  __shared__ float aw_l[32];
  __shared__ float spool[512];
  const int tid = threadIdx.x;
  const int b = blockIdx.x;
  const int n0 = b * 32;

  for (int idx = tid; idx < 1024; idx += 256) {
    const int n = idx >> 5, c4 = idx & 31;
    float4 v = F4(&O[(n0+n)*128 + c4*4]);
    OT[(c4*4+0)*33 + n] = v.x;
    OT[(c4*4+1)*33 + n] = v.y;
    OT[(c4*4+2)*33 + n] = v.z;
    OT[(c4*4+3)*33 + n] = v.w;
    *(float4*)&sx[n*132 + c4*4] = F4(&x[(n0+n)*128 + c4*4]);
  }
  __syncthreads();

  const int eg = tid & 7, cg = tid >> 3;
  const int e0 = eg*4, c0 = cg*4;
  const float* xp = &OT[e0];

  float acc[4][4];
#pragma unroll
  for (int j = 0; j < 4; ++j)
#pragma unroll
    for (int i = 0; i < 4; ++i) acc[j][i] = 0.f;

  float4 aA = F4(xp);
  float4 wA = F4(&woutT[c0]);
  float4 aB = F4(xp + 33);
  float4 wB = F4(&woutT[128 + c0]);
  for (int k = 0; k < 126; k += 2) {
    float4 aC = F4(xp + (k+2)*33);
    float4 wC = F4(&woutT[(k+2)*128 + c0]);
    GE_STEP(aA, wA);
    float4 aD = F4(xp + (k+3)*33);
    float4 wD = F4(&woutT[(k+3)*128 + c0]);
    GE_STEP(aB, wB);
    aA = aC; wA = wC;
    aB = aD; wB = wD;
  }
  GE_STEP(aA, wA);
  GE_STEP(aB, wB);
  __syncthreads();  // done reading OT -> alias as satt

  float* satt = OT;
  const float4 bl = F4(&bout[c0]);
#pragma unroll
  for (int j = 0; j < 4; ++j) {
    float4 o;
    o.x = acc[j][0] + bl.x;
    o.y = acc[j][1] + bl.y;
    o.z = acc[j][2] + bl.z;
    o.w = acc[j][3] + bl.w;
    *(float4*)&satt[(e0+j)*132 + c0] = o;
  }
  __syncthreads();

  { // aw logits: 8 threads/row
    const int a = tid >> 3, q8 = tid & 7;
    float sp = 0.f;
#pragma unroll
    for (int i = 0; i < 16; ++i)
      sp = fmaf(satt[a*132 + q8*16 + i], sx[a*132 + q8*16 + i], sp);
    sp += __shfl_xor(sp, 1);
    sp += __shfl_xor(sp, 2);
    sp += __shfl_xor(sp, 4);
    if (q8 == 0) aw_l[a] = sp;
  }
  __syncthreads();

  if (tid < 128) { // pooling per column
    float awr[32];
    float mxl = aw_l[0];
#pragma unroll
    for (int a = 1; a < 32; ++a) mxl = fmaxf(mxl, aw_l[a]);
    float se = 0.f;
#pragma unroll
    for (int a = 0; a < 32; ++a) { awr[a] = expf(aw_l[a] - mxl); se += awr[a]; }
    const float inv = 1.f / se;
    const int c = tid;
    float mx = -3.4e38f, sm = 0.f, wm = 0.f, ex = 0.f;
#pragma unroll
    for (int a = 0; a < 32; ++a) {
      const float v = satt[a*132 + c];
      mx = fmaxf(mx, v);
      sm += v;
      wm = fmaf(v, awr[a], wm);
      ex += sx[a*132 + c];
    }
    wm *= inv;
    const float mean = sm * 0.03125f;
    float s2 = 0.f;
#pragma unroll
    for (int a = 0; a < 32; ++a) {
      const float d = satt[a*132 + c] - mean;
      s2 = fmaf(d, d, s2);
    }
    const float stdp = sqrtf(s2 * (1.f/31.f));  // ddof=1
    expl[b*128 + c] = ex * 0.03125f;
    spool[c]       = wm;
    spool[128 + c] = mx;
    spool[256 + c] = mean;
    spool[384 + c] = stdp;
  }
  __syncthreads();

  if (tid < 64) { // proj -> learned
    const int k = tid >> 4, qq = tid & 15;
    const float* pk = pW + k*2048;
    float s = pb[k*16 + qq];
    for (int h2 = 0; h2 < 128; ++h2)
      s = fmaf(spool[k*128 + h2], pk[h2*16 + qq], s);
    lrn[b*64 + tid] = s;
  }
}

// ---------------- per-(property, molecule) gated MLP heads ----------------
__global__ __launch_bounds__(64) void head_kernel(
    const float* __restrict__ molf, const float* __restrict__ lrn,
    const float* __restrict__ expl,
    const float* __restrict__ mol_gate, const float* __restrict__ lrn_gate,
    const float* __restrict__ meW1, const float* __restrict__ meb1,
    const float* __restrict__ meW2, const float* __restrict__ meb2,
    const float* __restrict__ leW1, const float* __restrict__ leb1,
    const float* __restrict__ leW2, const float* __restrict__ leb2,
    const float* __restrict__ fW1, const float* __restrict__ fb1,
    const float* __restrict__ fW2, const float* __restrict__ fb2,
    const float* __restrict__ hW1, const float* __restrict__ hb1,
    const float* __restrict__ hW2, const float* __restrict__ hb2,
    float* __restrict__ out)
{
  const int b = blockIdx.x, p = blockIdx.y, t = threadIdx.x;
  __shared__ float sgm[200];
  __shared__ float sgl[64];
  __shared__ float sA[64];
  __shared__ float sB[64];
  __shared__ float scomb[256];
  __shared__ float sf1[128];
  __shared__ float sf2[64];

  for (int m = t; m < 200; m += 64)
    sgm[m] = molf[b*200 + m] * sigmoidf_(mol_gate[p*200 + m]);
  sgl[t] = lrn[b*64 + t] * sigmoidf_(lrn_gate[p*64 + t]);
  scomb[t]      = expl[b*128 + t];
  scomb[64 + t] = expl[b*128 + 64 + t];
  __syncthreads();

  {
    float s = meb1[p*64 + t];
    const float* w = meW1 + p*12800;
    for (int m = 0; m < 200; ++m) s = fmaf(sgm[m], w[m*64 + t], s);
    sA[t] = fmaxf(s, 0.f);
    float s2 = leb1[p*64 + t];
    const float* w2 = leW1 + p*4096;
#pragma unroll 8
    for (int m = 0; m < 64; ++m) s2 = fmaf(sgl[m], w2[m*64 + t], s2);
    sB[t] = fmaxf(s2, 0.f);
  }
  __syncthreads();
  {
    float s = meb2[p*64 + t];
    const float* w = meW2 + p*4096;
#pragma unroll 8
    for (int h = 0; h < 64; ++h) s = fmaf(sA[h], w[h*64 + t], s);
    scomb[128 + t] = s;
    float s2 = leb2[p*64 + t];
    const float* w2 = leW2 + p*4096;
#pragma unroll 8
    for (int h = 0; h < 64; ++h) s2 = fmaf(sB[h], w2[h*64 + t], s2);
    scomb[192 + t] = s2;
  }
  __syncthreads();
  {
    const float* w = fW1 + p*32768;
    float s0 = fb1[p*128 + t], s1 = fb1[p*128 + 64 + t];
    for (int c = 0; c < 256; ++c) {
      const float v = scomb[c];
      s0 = fmaf(v, w[c*128 + t], s0);
      s1 = fmaf(v, w[c*128 + 64 + t], s1);
    }
    sf1[t]      = fmaxf(s0, 0.f);
    sf1[64 + t] = fmaxf(s1, 0.f);
  }
  __syncthreads();
  {
    float s = fb2[p*64 + t];
    const float* w = fW2 + p*8192;
    for (int h = 0; h < 128; ++h) s = fmaf(sf1[h], w[h*64 + t], s);
    sf2[t] = s;
  }
  __syncthreads();
  float val = 0.f;
  if (t < 32) {
    float s = hb1[p*32 + t];
    const float* w = hW1 + p*2048;
#pragma unroll 8
    for (int h = 0; h < 64; ++h) s = fmaf(sf2[h], w[h*32 + t], s);
    val = fmaxf(s, 0.f) * hW2[p*32 + t];
  }
#pragma unroll
  for (int o = 1; o < 32; o <<= 1) val += __shfl_xor(val, o);
  if (t == 0) out[p*1024 + b] = val + hb2[p];
}

extern "C" void kernel_launch(void* const* d_in, const int* in_sizes, int n_in,
                              void* d_out, int out_size, void* d_ws, size_t ws_size,
                              hipStream_t stream) {
  const float* x_atoms    = (const float*)d_in[0];
  const float* pos        = (const float*)d_in[1];
  const float* molf       = (const float*)d_in[3];
  const float* emb_W      = (const float*)d_in[4];
  const float* emb_b      = (const float*)d_in[5];
  const float* mp_W1      = (const float*)d_in[6];
  const float* mp_b1      = (const float*)d_in[7];
  const float* mp_W2      = (const float*)d_in[8];
  const float* mp_b2      = (const float*)d_in[9];
  const float* ln_g       = (const float*)d_in[10];
  const float* ln_b       = (const float*)d_in[11];
  const float* attn_in_w  = (const float*)d_in[12];
  const float* attn_in_b  = (const float*)d_in[13];
  const float* attn_out_w = (const float*)d_in[14];
  const float* attn_out_b = (const float*)d_in[15];
  const float* pool_W     = (const float*)d_in[16];
  const float* pool_b     = (const float*)d_in[17];
  const float* mol_gate   = (const float*)d_in[18];
  const float* lrn_gate   = (const float*)d_in[19];
  const float* meW1       = (const float*)d_in[20];
  const float* meb1       = (const float*)d_in[21];
  const float* meW2       = (const float*)d_in[22];
  const float* meb2       = (const float*)d_in[23];
  const float* leW1       = (const float*)d_in[24];
  const float* leb1       = (const float*)d_in[25];
  const float* leW2       = (const float*)d_in[26];
  const float* leb2       = (const float*)d_in[27];
  const float* fW1        = (const float*)d_in[28];
  const float* fb1        = (const float*)d_in[29];
  const float* fW2        = (const float*)d_in[30];
  const float* fb2        = (const float*)d_in[31];
  const float* hW1        = (const float*)d_in[32];
  const float* hb1        = (const float*)d_in[33];
  const float* hW2        = (const float*)d_in[34];
  const float* hb2        = (const float*)d_in[35];
  const int*   ei         = (const int*)d_in[36];

  float* ws      = (float*)d_ws;
  float* x       = ws;                       // NN*128
  float* P       = x + (size_t)NN*128;       // NN*128
  float* Q       = P + (size_t)NN*128;       // NN*128
  float* csr_df  = Q + (size_t)NN*128;       // NE*3
  int*   csr_src = (int*)(csr_df + (size_t)NE*3); // NE
  int*   cnt_i   = csr_src + NE;             // NN
  int*   csr_off = cnt_i + NN;               // NN+1
  int*   cur     = csr_off + NN + 1;         // NN
  float* lrn     = (float*)(cur + NN);       // NB*64
  float* expl    = lrn + NB*64;              // NB*128
  float* dv      = expl + NB*128;            // NN*128
  float* winT    = dv + (size_t)NN*128;      // 128*384
  float* woutT   = winT + 128*384;           // 128*128

  // aliases (mol path runs after the layer loop, P/Q free)
  float* dq = P;
  float* dk = Q;
  float* O  = Q;   // attn reads dk rows into LDS before overwriting same rows

  hipMemsetAsync(cnt_i, 0, (size_t)NN*sizeof(int), stream);

  embed_kernel<<<NN, 128, 0, stream>>>(x_atoms, emb_W, emb_b, x);
  hist_kernel<<<NE/256, 256, 0, stream>>>(ei, cnt_i);
  scan_kernel<<<1, 1024, 0, stream>>>(cnt_i, csr_off, cur);
  scatter_kernel<<<NE/256, 256, 0, stream>>>(pos, ei, cur, csr_src, csr_df);
  transpose_kernel<<<dim3(4, 12), 256, 0, stream>>>(attn_in_w, winT, 384, 128);
  transpose_kernel<<<dim3(4, 4), 256, 0, stream>>>(attn_out_w, woutT, 128, 128);

  for (int l = 0; l < 3; ++l) {
    const float* W1l = mp_W1 + (size_t)l*259*128;
    pq_kernel<<<NN/32, 256, 0, stream>>>(x, W1l, mp_b1 + l*128, P, Q);
    agg_kernel<<<NN/4, 256, 0, stream>>>(P, Q, csr_off, csr_src, csr_df, W1l);
    gemm_ln_kernel<<<NN/32, 256, 0, stream>>>(P, mp_W2 + (size_t)l*128*128, mp_b2 + l*128,
                                              csr_off, ln_g + l*128, ln_b + l*128, x);
  }

  qkv_kernel<<<NN/32, 256, 0, stream>>>(x, winT, attn_in_b, dq, dk, dv);
  attn_kernel<<<NB, 128, 0, stream>>>(dq, dk, dv, O);
  attout_pool_kernel<<<NB, 256, 0, stream>>>(O, woutT, attn_out_b, x,
                                             pool_W, pool_b, expl, lrn);
  head_kernel<<<dim3(NB, 4), 64, 0, stream>>>(molf, lrn, expl, mol_gate, lrn_gate,
      meW1, meb1, meW2, meb2, leW1, leb1, leW2, leb2,
      fW1, fb1, fW2, fb2, hW1, hb1, hW2, hb2, (float*)d_out);
}

// Round 6
// 449.262 us; speedup vs baseline: 1.6159x; 1.6159x over previous
//
#include <hip/hip_runtime.h>

#define NE 524288
#define NN 32768
#define NB 1024

#define F4(p) (*(const float4*)(p))

typedef __bf16 bf16x8 __attribute__((ext_vector_type(8)));
typedef float  f32x4  __attribute__((ext_vector_type(4)));

__device__ __forceinline__ float sigmoidf_(float v) { return 1.f / (1.f + expf(-v)); }

__device__ __forceinline__ void bf16split(float f, short &hi, short &lo) {
  unsigned u = __float_as_uint(f);
  unsigned rh = (u + 0x7FFFu + ((u >> 16) & 1u)) >> 16;
  float fh = __uint_as_float(rh << 16);
  float fl = f - fh;
  unsigned u2 = __float_as_uint(fl);
  unsigned rl = (u2 + 0x7FFFu + ((u2 >> 16) & 1u)) >> 16;
  hi = (short)rh; lo = (short)rl;
}

__device__ __forceinline__ void ld32(float* xr, const float* p) {
#pragma unroll
  for (int i = 0; i < 32; i += 4) {
    float4 v = F4(&p[i]);
    xr[i] = v.x; xr[i+1] = v.y; xr[i+2] = v.z; xr[i+3] = v.w;
  }
}

__device__ __forceinline__ float dot32r(const float* __restrict__ w, const float* xr) {
  float s = 0.f;
#pragma unroll
  for (int i = 0; i < 32; i += 4) {
    float4 ww = F4(&w[i]);
    s = fmaf(xr[i],   ww.x, s);
    s = fmaf(xr[i+1], ww.y, s);
    s = fmaf(xr[i+2], ww.z, s);
    s = fmaf(xr[i+3], ww.w, s);
  }
  return s;
}

// ---------------- embedding ----------------
__global__ __launch_bounds__(128) void embed_kernel(
    const float* __restrict__ xa, const float* __restrict__ W,
    const float* __restrict__ b, float* __restrict__ x)
{
  __shared__ float a[64];
  const int n = blockIdx.x, t = threadIdx.x;
  if (t < 64) a[t] = xa[n*64 + t];
  __syncthreads();
  float s = b[t];
#pragma unroll 8
  for (int f = 0; f < 64; ++f) s = fmaf(a[f], W[f*128 + t], s);
  x[n*128 + t] = s;
}

// ---------------- CSR build ----------------
__global__ __launch_bounds__(256) void hist_kernel(const int* __restrict__ ei, int* __restrict__ cnt) {
  const int e = blockIdx.x*256 + threadIdx.x;
  atomicAdd(&cnt[ei[NE + e]], 1);
}

__global__ __launch_bounds__(1024) void scan_kernel(
    const int* __restrict__ cnt, int* __restrict__ off, int* __restrict__ cur)
{
  __shared__ int wsum[16];
  const int t = threadIdx.x;
  int local[32];
  const int base = t*32;
  int s = 0;
#pragma unroll
  for (int i = 0; i < 32; ++i) { local[i] = cnt[base+i]; s += local[i]; }
  int pre = s;
  const int lane = t & 63;
#pragma unroll
  for (int o = 1; o < 64; o <<= 1) { int v = __shfl_up(pre, o); if (lane >= o) pre += v; }
  if (lane == 63) wsum[t >> 6] = pre;
  __syncthreads();
  if (t == 0) { int a = 0; for (int w = 0; w < 16; ++w) { int v = wsum[w]; wsum[w] = a; a += v; } }
  __syncthreads();
  int excl = wsum[t >> 6] + pre - s;
#pragma unroll
  for (int i = 0; i < 32; ++i) { off[base+i] = excl; cur[base+i] = excl; excl += local[i]; }
  if (t == 1023) off[NN] = excl;
}

__global__ __launch_bounds__(256) void scatter_kernel(
    const float* __restrict__ pos, const int* __restrict__ ei,
    int* __restrict__ cur, int* __restrict__ csr_src, float* __restrict__ csr_df)
{
  const int e = blockIdx.x*256 + threadIdx.x;
  const int s = ei[e];
  const int d = ei[NE + e];
  float dx = pos[d*3+0] - pos[s*3+0];
  float dy = pos[d*3+1] - pos[s*3+1];
  float dz = pos[d*3+2] - pos[s*3+2];
  float dist = sqrtf(dx*dx + dy*dy + dz*dz + 1e-12f);
  const int slot = atomicAdd(&cur[d], 1);
  csr_src[slot] = s;
  csr_df[slot*3+0] = dist;
  csr_df[slot*3+1] = 1.f/(1.f + dist);
  csr_df[slot*3+2] = expf(-dist);
}

// ---------------- weight prep: split to bf16 hi/lo in MFMA-frag-major layout ----------------
// out index i: ((kc*NT + t)*64 + lane)*8 + j  holds  B[k][n],
//   k = kc*32 + (lane>>4)*8 + j,  n = t*16 + (lane&15)
// segments (element offsets): w1ab l=0..2 @ l*32768 (N=256); w2 l @ 98304+l*16384 (N=128);
//   winT @ 147456 (N=384); woutT @ 196608 (N=128). total 212992.
__device__ __forceinline__ void pack_decode(int r, int N, int &k, int &n) {
  const int j = r & 7, lane = (r >> 3) & 63, rest = r >> 9;
  const int NT = N >> 4;
  const int t = rest % NT, kc = rest / NT;
  k = kc*32 + (lane >> 4)*8 + j;
  n = t*16 + (lane & 15);
}

__global__ __launch_bounds__(256) void prep_kernel(
    const float* __restrict__ mp_W1, const float* __restrict__ mp_W2,
    const float* __restrict__ win, const float* __restrict__ wout,
    const float* __restrict__ mp_b1,
    short* __restrict__ bh, short* __restrict__ bl, float* __restrict__ pqbias)
{
  const int i = blockIdx.x*256 + threadIdx.x;
  if (i < 768) { const int l = i >> 8, t = i & 255; pqbias[i] = t < 128 ? mp_b1[l*128 + t] : 0.f; }
  if (i >= 212992) return;
  int k, n; float v;
  if (i < 98304) {
    const int l = i / 32768, r = i % 32768;
    pack_decode(r, 256, k, n);
    const float* W = mp_W1 + (size_t)l*259*128;
    v = (n < 128) ? W[k*128 + n] : W[(128+k)*128 + (n-128)];
  } else if (i < 147456) {
    const int q = i - 98304, l = q / 16384, r = q % 16384;
    pack_decode(r, 128, k, n);
    v = mp_W2[(size_t)l*16384 + k*128 + n];
  } else if (i < 196608) {
    const int r = i - 147456;
    pack_decode(r, 384, k, n);
    v = win[n*128 + k];
  } else {
    const int r = i - 196608;
    pack_decode(r, 128, k, n);
    v = wout[n*128 + k];
  }
  short h, lo; bf16split(v, h, lo);
  bh[i] = h; bl[i] = lo;
}

// ---------------- generic MFMA GEMM: C[M][ncols] = A[M][128] @ B + bias ----------------
// block = 4 waves; wave = 32 rows x 64 cols; grid = (M/128, ncols/64). split-bf16 3-term.
__global__ __launch_bounds__(256, 2) void mfma_gemm_kernel(
    const float* __restrict__ A, int lda,
    const short* __restrict__ Bh, const short* __restrict__ Bl,
    const float* __restrict__ bias, float* __restrict__ C, int ncols)
{
  const int lane = threadIdx.x & 63, wid = threadIdx.x >> 6;
  const int m0 = blockIdx.x * 128 + wid * 32;
  const int n0 = blockIdx.y * 64;
  const int NT = ncols >> 4;
  const int cl = lane & 15, kg = lane >> 4;

  bf16x8 Ah[2][4], Al[2][4];
#pragma unroll
  for (int s = 0; s < 2; ++s)
#pragma unroll
    for (int kc = 0; kc < 4; ++kc) {
      const float* ap = &A[(size_t)(m0 + s*16 + cl)*lda + kc*32 + kg*8];
      const float4 f0 = F4(ap), f1 = F4(ap + 4);
      const float fv[8] = {f0.x,f0.y,f0.z,f0.w,f1.x,f1.y,f1.z,f1.w};
      union { short s[8]; bf16x8 b; } uh, ul;
#pragma unroll
      for (int j = 0; j < 8; ++j) bf16split(fv[j], uh.s[j], ul.s[j]);
      Ah[s][kc] = uh.b; Al[s][kc] = ul.b;
    }

  f32x4 acc[2][4];
#pragma unroll
  for (int s = 0; s < 2; ++s)
#pragma unroll
    for (int t = 0; t < 4; ++t) acc[s][t] = (f32x4){0.f,0.f,0.f,0.f};

#pragma unroll
  for (int kc = 0; kc < 4; ++kc) {
    bf16x8 Bfh[4], Bfl[4];
#pragma unroll
    for (int t = 0; t < 4; ++t) {
      const size_t off = (((size_t)(kc*NT + (n0 >> 4) + t))*64 + lane)*8;
      Bfh[t] = *(const bf16x8*)&Bh[off];
      Bfl[t] = *(const bf16x8*)&Bl[off];
    }
#pragma unroll
    for (int s = 0; s < 2; ++s)
#pragma unroll
      for (int t = 0; t < 4; ++t)
        acc[s][t] = __builtin_amdgcn_mfma_f32_16x16x32_bf16(Ah[s][kc], Bfh[t], acc[s][t], 0, 0, 0);
#pragma unroll
    for (int s = 0; s < 2; ++s)
#pragma unroll
      for (int t = 0; t < 4; ++t)
        acc[s][t] = __builtin_amdgcn_mfma_f32_16x16x32_bf16(Ah[s][kc], Bfl[t], acc[s][t], 0, 0, 0);
#pragma unroll
    for (int s = 0; s < 2; ++s)
#pragma unroll
      for (int t = 0; t < 4; ++t)
        acc[s][t] = __builtin_amdgcn_mfma_f32_16x16x32_bf16(Al[s][kc], Bfh[t], acc[s][t], 0, 0, 0);
  }

#pragma unroll
  for (int t = 0; t < 4; ++t) {
    const int col = n0 + t*16 + cl;
    const float bv = bias[col];
#pragma unroll
    for (int s = 0; s < 2; ++s) {
      const int rbase = m0 + s*16 + kg*4;
#pragma unroll
      for (int r = 0; r < 4; ++r)
        C[(size_t)(rbase + r)*ncols + col] = acc[s][t][r] + bv;
    }
  }
}

// ---------------- MFMA GEMM + residual + LN: x <- LN(A@W2 + (deg>0)*b2 + x) ----------------
// block = 4 waves; wave = 16 rows x 128 cols; grid = M/64.
__global__ __launch_bounds__(256, 2) void mfma_gemm_ln_kernel(
    const float* __restrict__ A, int lda,
    const short* __restrict__ Bh, const short* __restrict__ Bl,
    const float* __restrict__ b2, const int* __restrict__ csr_off,
    const float* __restrict__ g, const float* __restrict__ bb,
    float* __restrict__ x)
{
  const int lane = threadIdx.x & 63, wid = threadIdx.x >> 6;
  const int m0 = blockIdx.x * 64 + wid * 16;
  const int cl = lane & 15, kg = lane >> 4;

  bf16x8 Ah[4], Al[4];
#pragma unroll
  for (int kc = 0; kc < 4; ++kc) {
    const float* ap = &A[(size_t)(m0 + cl)*lda + kc*32 + kg*8];
    const float4 f0 = F4(ap), f1 = F4(ap + 4);
    const float fv[8] = {f0.x,f0.y,f0.z,f0.w,f1.x,f1.y,f1.z,f1.w};
    union { short s[8]; bf16x8 b; } uh, ul;
#pragma unroll
    for (int j = 0; j < 8; ++j) bf16split(fv[j], uh.s[j], ul.s[j]);
    Ah[kc] = uh.b; Al[kc] = ul.b;
  }

  f32x4 acc[8];
#pragma unroll
  for (int t = 0; t < 8; ++t) acc[t] = (f32x4){0.f,0.f,0.f,0.f};

#pragma unroll
  for (int kc = 0; kc < 4; ++kc) {
    bf16x8 Bfh[8], Bfl[8];
#pragma unroll
    for (int t = 0; t < 8; ++t) {
      const size_t off = (((size_t)(kc*8 + t))*64 + lane)*8;
      Bfh[t] = *(const bf16x8*)&Bh[off];
      Bfl[t] = *(const bf16x8*)&Bl[off];
    }
#pragma unroll
    for (int t = 0; t < 8; ++t)
      acc[t] = __builtin_amdgcn_mfma_f32_16x16x32_bf16(Ah[kc], Bfh[t], acc[t], 0, 0, 0);
#pragma unroll
    for (int t = 0; t < 8; ++t)
      acc[t] = __builtin_amdgcn_mfma_f32_16x16x32_bf16(Ah[kc], Bfl[t], acc[t], 0, 0, 0);
#pragma unroll
    for (int t = 0; t < 8; ++t)
      acc[t] = __builtin_amdgcn_mfma_f32_16x16x32_bf16(Al[kc], Bfh[t], acc[t], 0, 0, 0);
  }

  // epilogue: y = acc + s*b2 + x ; LN per row (rows r0..r0+3 held by this lane group)
  const int r0 = m0 + kg*4;
  float sflag[4];
#pragma unroll
  for (int r = 0; r < 4; ++r)
    sflag[r] = (csr_off[r0 + r + 1] > csr_off[r0 + r]) ? 1.f : 0.f;

  float ps[4] = {0.f,0.f,0.f,0.f}, pq[4] = {0.f,0.f,0.f,0.f};
  float yv[8][4];
#pragma unroll
  for (int t = 0; t < 8; ++t) {
    const int col = t*16 + cl;
    const float b2v = b2[col];
#pragma unroll
    for (int r = 0; r < 4; ++r) {
      const float y = acc[t][r] + sflag[r]*b2v + x[(size_t)(r0 + r)*128 + col];
      yv[t][r] = y;
      ps[r] += y;
      pq[r] = fmaf(y, y, pq[r]);
    }
  }
#pragma unroll
  for (int o = 1; o < 16; o <<= 1) {
#pragma unroll
    for (int r = 0; r < 4; ++r) { ps[r] += __shfl_xor(ps[r], o); pq[r] += __shfl_xor(pq[r], o); }
  }
#pragma unroll
  for (int r = 0; r < 4; ++r) {
    const float mu = ps[r] * (1.f/128.f);
    const float var = pq[r]*(1.f/128.f) - mu*mu;
    const float rstd = rsqrtf(var + 1e-5f);
#pragma unroll
    for (int t = 0; t < 8; ++t) {
      const int col = t*16 + cl;
      x[(size_t)(r0 + r)*128 + col] = (yv[t][r] - mu)*rstd*g[col] + bb[col];
    }
  }
}

// ---------------- aggregation on PQc[n][256]: P slot <- mean_e relu(P[n]+Q[src]+df@W1c) ----------------
__global__ __launch_bounds__(256) void agg_kernel(
    float* __restrict__ PQc,
    const int* __restrict__ csr_off, const int* __restrict__ csr_src,
    const float* __restrict__ csr_df, const float* __restrict__ W1)
{
  const int tid = threadIdx.x;
  const int node = blockIdx.x*4 + (tid >> 6);
  const int lane = tid & 63;
  const int c0 = lane*2;
  const int off0 = csr_off[node], off1 = csr_off[node+1];

  const float* __restrict__ w1c = W1 + 256*128;
  const float w00 = w1c[c0],       w01 = w1c[c0+1];
  const float w10 = w1c[128+c0],   w11 = w1c[128+c0+1];
  const float w20 = w1c[256+c0],   w21 = w1c[256+c0+1];
  const float2 p = *(const float2*)&PQc[(size_t)node*256 + c0];

  float a0 = 0.f, a1 = 0.f;
  int e = off0;
  for (; e + 4 <= off1; e += 4) {
#pragma unroll
    for (int j = 0; j < 4; ++j) {
      const int src = csr_src[e+j];
      const float d0 = csr_df[(e+j)*3+0];
      const float d1 = csr_df[(e+j)*3+1];
      const float d2 = csr_df[(e+j)*3+2];
      const float2 q = *(const float2*)&PQc[(size_t)src*256 + 128 + c0];
      float h0 = p.x + q.x;
      h0 = fmaf(d0, w00, h0); h0 = fmaf(d1, w10, h0); h0 = fmaf(d2, w20, h0);
      float h1 = p.y + q.y;
      h1 = fmaf(d0, w01, h1); h1 = fmaf(d1, w11, h1); h1 = fmaf(d2, w21, h1);
      a0 += fmaxf(h0, 0.f);
      a1 += fmaxf(h1, 0.f);
    }
  }
  for (; e < off1; ++e) {
    const int src = csr_src[e];
    const float d0 = csr_df[e*3+0];
    const float d1 = csr_df[e*3+1];
    const float d2 = csr_df[e*3+2];
    const float2 q = *(const float2*)&PQc[(size_t)src*256 + 128 + c0];
    float h0 = p.x + q.x;
    h0 = fmaf(d0, w00, h0); h0 = fmaf(d1, w10, h0); h0 = fmaf(d2, w20, h0);
    float h1 = p.y + q.y;
    h1 = fmaf(d0, w01, h1); h1 = fmaf(d1, w11, h1); h1 = fmaf(d2, w21, h1);
    a0 += fmaxf(h0, 0.f);
    a1 += fmaxf(h1, 0.f);
  }
  const int deg = off1 - off0;
  const float rc = deg > 0 ? 1.f/(float)deg : 1.f;
  *(float2*)&PQc[(size_t)node*256 + c0] = make_float2(a0*rc, a1*rc);
}

// ---------------- per-molecule attention on dqkv[n][384]; O written into dv slot ----------------
__global__ __launch_bounds__(128) void attn_kernel(float* __restrict__ dqkv)
{
  __shared__ float sk[32*132];
  __shared__ float sv[32*132];
  const int tid = threadIdx.x;
  const int b = blockIdx.x;

  for (int idx = tid; idx < 1024; idx += 128) {
    const int a = idx >> 5, c4 = idx & 31;
    *(float4*)&sk[a*132 + c4*4] = F4(&dqkv[(size_t)(b*32+a)*384 + 128 + c4*4]);
    *(float4*)&sv[a*132 + c4*4] = F4(&dqkv[(size_t)(b*32+a)*384 + 256 + c4*4]);
  }
  __syncthreads();

  const int h = tid >> 5, qr = tid & 31;
  float qreg[32];
  ld32(qreg, &dqkv[(size_t)(b*32+qr)*384 + h*32]);

  float sc[32];
#pragma unroll
  for (int k = 0; k < 32; ++k)
    sc[k] = dot32r(&sk[k*132 + h*32], qreg) * 0.17677669529663687f;
  float mx = sc[0];
#pragma unroll
  for (int k = 1; k < 32; ++k) mx = fmaxf(mx, sc[k]);
  float se = 0.f;
#pragma unroll
  for (int k = 0; k < 32; ++k) { sc[k] = expf(sc[k] - mx); se += sc[k]; }
  const float inv = 1.f / se;

  __syncthreads();  // done reading sk; reuse as O staging

  float od[32];
#pragma unroll
  for (int i = 0; i < 32; ++i) od[i] = 0.f;
#pragma unroll 4
  for (int k = 0; k < 32; ++k) {
    const float w = sc[k] * inv;
    const float* vr = &sv[k*132 + h*32];
#pragma unroll
    for (int i = 0; i < 32; i += 4) {
      float4 v = F4(&vr[i]);
      od[i]   = fmaf(w, v.x, od[i]);
      od[i+1] = fmaf(w, v.y, od[i+1]);
      od[i+2] = fmaf(w, v.z, od[i+2]);
      od[i+3] = fmaf(w, v.w, od[i+3]);
    }
  }
#pragma unroll
  for (int i = 0; i < 32; i += 4)
    *(float4*)&sk[qr*132 + h*32 + i] = make_float4(od[i], od[i+1], od[i+2], od[i+3]);
  __syncthreads();

  for (int idx = tid; idx < 1024; idx += 128) {
    const int a = idx >> 5, c4 = idx & 31;
    *(float4*)&dqkv[(size_t)(b*32+a)*384 + 256 + c4*4] = F4(&sk[a*132 + c4*4]);
  }
}

// ---------------- per-molecule pooling + proj (att linear [NN][128]) ----------------
__global__ __launch_bounds__(128) void pool_kernel(
    const float* __restrict__ att, const float* __restrict__ x,
    const float* __restrict__ pW, const float* __restrict__ pb,
    float* __restrict__ expl, float* __restrict__ lrn)
{
  __shared__ float satt[32*132];
  __shared__ float sx[32*132];
  __shared__ float aw_l[32];
  __shared__ float spool[512];
  const int tid = threadIdx.x;
  const int b = blockIdx.x;

  for (int idx = tid; idx < 1024; idx += 128) {
    const int a = idx >> 5, c4 = idx & 31;
    *(float4*)&satt[a*132 + c4*4] = F4(&att[(size_t)(b*32+a)*128 + c4*4]);
    *(float4*)&sx[a*132 + c4*4]   = F4(&x[(size_t)(b*32+a)*128 + c4*4]);
  }
  __syncthreads();

  {
    const int a = tid >> 2, q4 = tid & 3;
    float sp = 0.f;
#pragma unroll
    for (int i = 0; i < 32; ++i)
      sp = fmaf(satt[a*132 + q4*32 + i], sx[a*132 + q4*32 + i], sp);
    sp += __shfl_xor(sp, 1);
    sp += __shfl_xor(sp, 2);
    if (q4 == 0) aw_l[a] = sp;
  }
  __syncthreads();

  {
    float awr[32];
    float mxl = aw_l[0];
#pragma unroll
    for (int a = 1; a < 32; ++a) mxl = fmaxf(mxl, aw_l[a]);
    float se = 0.f;
#pragma unroll
    for (int a = 0; a < 32; ++a) { awr[a] = expf(aw_l[a] - mxl); se += awr[a]; }
    const float inv = 1.f / se;
    const int c = tid;
    float mx = -3.4e38f, sm = 0.f, wm = 0.f, ex = 0.f;
#pragma unroll
    for (int a = 0; a < 32; ++a) {
      const float v = satt[a*132 + c];
      mx = fmaxf(mx, v);
      sm += v;
      wm = fmaf(v, awr[a], wm);
      ex += sx[a*132 + c];
    }
    wm *= inv;
    const float mean = sm * 0.03125f;
    float s2 = 0.f;
#pragma unroll
    for (int a = 0; a < 32; ++a) {
      const float d = satt[a*132 + c] - mean;
      s2 = fmaf(d, d, s2);
    }
    const float stdp = sqrtf(s2 * (1.f/31.f));  // ddof=1
    expl[b*128 + c] = ex * 0.03125f;
    spool[c]       = wm;
    spool[128 + c] = mx;
    spool[256 + c] = mean;
    spool[384 + c] = stdp;
  }
  __syncthreads();

  if (tid < 64) {
    const int k = tid >> 4, qq = tid & 15;
    const float* pk = pW + k*2048;
    float s = pb[k*16 + qq];
    for (int h2 = 0; h2 < 128; ++h2)
      s = fmaf(spool[k*128 + h2], pk[h2*16 + qq], s);
    lrn[b*64 + tid] = s;
  }
}

// ---------------- per-(property, molecule) gated MLP heads ----------------
__global__ __launch_bounds__(64) void head_kernel(
    const float* __restrict__ molf, const float* __restrict__ lrn,
    const float* __restrict__ expl,
    const float* __restrict__ mol_gate, const float* __restrict__ lrn_gate,
    const float* __restrict__ meW1, const float* __restrict__ meb1,
    const float* __restrict__ meW2, const float* __restrict__ meb2,
    const float* __restrict__ leW1, const float* __restrict__ leb1,
    const float* __restrict__ leW2, const float* __restrict__ leb2,
    const float* __restrict__ fW1, const float* __restrict__ fb1,
    const float* __restrict__ fW2, const float* __restrict__ fb2,
    const float* __restrict__ hW1, const float* __restrict__ hb1,
    const float* __restrict__ hW2, const float* __restrict__ hb2,
    float* __restrict__ out)
{
  const int b = blockIdx.x, p = blockIdx.y, t = threadIdx.x;
  __shared__ float sgm[200];
  __shared__ float sgl[64];
  __shared__ float sA[64];
  __shared__ float sB[64];
  __shared__ float scomb[256];
  __shared__ float sf1[128];
  __shared__ float sf2[64];

  for (int m = t; m < 200; m += 64)
    sgm[m] = molf[b*200 + m] * sigmoidf_(mol_gate[p*200 + m]);
  sgl[t] = lrn[b*64 + t] * sigmoidf_(lrn_gate[p*64 + t]);
  scomb[t]      = expl[b*128 + t];
  scomb[64 + t] = expl[b*128 + 64 + t];
  __syncthreads();

  {
    float s = meb1[p*64 + t];
    const float* w = meW1 + p*12800;
    for (int m = 0; m < 200; ++m) s = fmaf(sgm[m], w[m*64 + t], s);
    sA[t] = fmaxf(s, 0.f);
    float s2 = leb1[p*64 + t];
    const float* w2 = leW1 + p*4096;
#pragma unroll 8
    for (int m = 0; m < 64; ++m) s2 = fmaf(sgl[m], w2[m*64 + t], s2);
    sB[t] = fmaxf(s2, 0.f);
  }
  __syncthreads();
  {
    float s = meb2[p*64 + t];
    const float* w = meW2 + p*4096;
#pragma unroll 8
    for (int h = 0; h < 64; ++h) s = fmaf(sA[h], w[h*64 + t], s);
    scomb[128 + t] = s;
    float s2 = leb2[p*64 + t];
    const float* w2 = leW2 + p*4096;
#pragma unroll 8
    for (int h = 0; h < 64; ++h) s2 = fmaf(sB[h], w2[h*64 + t], s2);
    scomb[192 + t] = s2;
  }
  __syncthreads();
  {
    const float* w = fW1 + p*32768;
    float s0 = fb1[p*128 + t], s1 = fb1[p*128 + 64 + t];
    for (int c = 0; c < 256; ++c) {
      const float v = scomb[c];
      s0 = fmaf(v, w[c*128 + t], s0);
      s1 = fmaf(v, w[c*128 + 64 + t], s1);
    }
    sf1[t]      = fmaxf(s0, 0.f);
    sf1[64 + t] = fmaxf(s1, 0.f);
  }
  __syncthreads();
  {
    float s = fb2[p*64 + t];
    const float* w = fW2 + p*8192;
    for (int h = 0; h < 128; ++h) s = fmaf(sf1[h], w[h*64 + t], s);
    sf2[t] = s;
  }
  __syncthreads();
  float val = 0.f;
  if (t < 32) {
    float s = hb1[p*32 + t];
    const float* w = hW1 + p*2048;
#pragma unroll 8
    for (int h = 0; h < 64; ++h) s = fmaf(sf2[h], w[h*32 + t], s);
    val = fmaxf(s, 0.f) * hW2[p*32 + t];
  }
#pragma unroll
  for (int o = 1; o < 32; o <<= 1) val += __shfl_xor(val, o);
  if (t == 0) out[p*1024 + b] = val + hb2[p];
}

extern "C" void kernel_launch(void* const* d_in, const int* in_sizes, int n_in,
                              void* d_out, int out_size, void* d_ws, size_t ws_size,
                              hipStream_t stream) {
  const float* x_atoms    = (const float*)d_in[0];
  const float* pos        = (const float*)d_in[1];
  const float* molf       = (const float*)d_in[3];
  const float* emb_W      = (const float*)d_in[4];
  const float* emb_b      = (const float*)d_in[5];
  const float* mp_W1      = (const float*)d_in[6];
  const float* mp_b1      = (const float*)d_in[7];
  const float* mp_W2      = (const float*)d_in[8];
  const float* mp_b2      = (const float*)d_in[9];
  const float* ln_g       = (const float*)d_in[10];
  const float* ln_b       = (const float*)d_in[11];
  const float* attn_in_w  = (const float*)d_in[12];
  const float* attn_in_b  = (const float*)d_in[13];
  const float* attn_out_w = (const float*)d_in[14];
  const float* attn_out_b = (const float*)d_in[15];
  const float* pool_W     = (const float*)d_in[16];
  const float* pool_b     = (const float*)d_in[17];
  const float* mol_gate   = (const float*)d_in[18];
  const float* lrn_gate   = (const float*)d_in[19];
  const float* meW1       = (const float*)d_in[20];
  const float* meb1       = (const float*)d_in[21];
  const float* meW2       = (const float*)d_in[22];
  const float* meb2       = (const float*)d_in[23];
  const float* leW1       = (const float*)d_in[24];
  const float* leb1       = (const float*)d_in[25];
  const float* leW2       = (const float*)d_in[26];
  const float* leb2       = (const float*)d_in[27];
  const float* fW1        = (const float*)d_in[28];
  const float* fb1        = (const float*)d_in[29];
  const float* fW2        = (const float*)d_in[30];
  const float* fb2        = (const float*)d_in[31];
  const float* hW1        = (const float*)d_in[32];
  const float* hb1        = (const float*)d_in[33];
  const float* hW2        = (const float*)d_in[34];
  const float* hb2        = (const float*)d_in[35];
  const int*   ei         = (const int*)d_in[36];

  float* ws      = (float*)d_ws;
  float* x       = ws;                              // NN*128
  float* PQc     = x + (size_t)NN*128;              // overlay region NN*384 (PQc uses NN*256)
  float* dqkv    = PQc;                             // NN*384 (alias; PQc dead when used)
  float* att     = PQc + (size_t)NN*384;            // NN*128
  float* csr_df  = att + (size_t)NN*128;            // NE*3
  int*   csr_src = (int*)(csr_df + (size_t)NE*3);   // NE
  int*   cnt_i   = csr_src + NE;                    // NN
  int*   csr_off = cnt_i + NN;                      // NN+1
  int*   cur     = csr_off + NN + 1;                // NN
  float* lrn     = (float*)(cur + NN);              // NB*64
  float* expl    = lrn + NB*64;                     // NB*128
  float* pqbias  = expl + NB*128;                   // 3*256
  short* bh      = (short*)(pqbias + 768);          // 212992 shorts
  short* bl      = bh + 212992;                     // 212992 shorts

  // packed-weight segment offsets (shorts)
  const int W1AB_OFF = 0;        // + l*32768, N=256
  const int W2_OFF   = 98304;    // + l*16384, N=128
  const int WIN_OFF  = 147456;   // N=384
  const int WOUT_OFF = 196608;   // N=128

  hipMemsetAsync(cnt_i, 0, (size_t)NN*sizeof(int), stream);

  embed_kernel<<<NN, 128, 0, stream>>>(x_atoms, emb_W, emb_b, x);
  hist_kernel<<<NE/256, 256, 0, stream>>>(ei, cnt_i);
  scan_kernel<<<1, 1024, 0, stream>>>(cnt_i, csr_off, cur);
  scatter_kernel<<<NE/256, 256, 0, stream>>>(pos, ei, cur, csr_src, csr_df);
  prep_kernel<<<(212992 + 255)/256, 256, 0, stream>>>(mp_W1, mp_W2, attn_in_w, attn_out_w,
                                                      mp_b1, bh, bl, pqbias);

  for (int l = 0; l < 3; ++l) {
    mfma_gemm_kernel<<<dim3(NN/128, 4), 256, 0, stream>>>(
        x, 128, bh + W1AB_OFF + l*32768, bl + W1AB_OFF + l*32768,
        pqbias + l*256, PQc, 256);
    agg_kernel<<<NN/4, 256, 0, stream>>>(PQc, csr_off, csr_src, csr_df,
                                         mp_W1 + (size_t)l*259*128);
    mfma_gemm_ln_kernel<<<NN/64, 256, 0, stream>>>(
        PQc, 256, bh + W2_OFF + l*16384, bl + W2_OFF + l*16384,
        mp_b2 + l*128, csr_off, ln_g + l*128, ln_b + l*128, x);
  }

  // qkv -> dqkv[N][384] (overlays dead PQc)
  mfma_gemm_kernel<<<dim3(NN/128, 6), 256, 0, stream>>>(
      x, 128, bh + WIN_OFF, bl + WIN_OFF, attn_in_b, dqkv, 384);
  attn_kernel<<<NB, 128, 0, stream>>>(dqkv);
  // attended = O @ woutT + bout ; A = O in dv slot (stride 384)
  mfma_gemm_kernel<<<dim3(NN/128, 2), 256, 0, stream>>>(
      dqkv + 256, 384, bh + WOUT_OFF, bl + WOUT_OFF, attn_out_b, att, 128);
  pool_kernel<<<NB, 128, 0, stream>>>(att, x, pool_W, pool_b, expl, lrn);
  head_kernel<<<dim3(NB, 4), 64, 0, stream>>>(molf, lrn, expl, mol_gate, lrn_gate,
      meW1, meb1, meW2, meb2, leW1, leb1, leW2, leb2,
      fW1, fb1, fW2, fb2, hW1, hb1, hW2, hb2, (float*)d_out);
}

// Round 7
// 429.046 us; speedup vs baseline: 1.6920x; 1.0471x over previous
//
#include <hip/hip_runtime.h>

#define NE 524288
#define NN 32768
#define NB 1024

#define F4(p) (*(const float4*)(p))

typedef __bf16 bf16x8 __attribute__((ext_vector_type(8)));
typedef float  f32x4  __attribute__((ext_vector_type(4)));

__device__ __forceinline__ float sigmoidf_(float v) { return 1.f / (1.f + expf(-v)); }

__device__ __forceinline__ void bf16split(float f, short &hi, short &lo) {
  unsigned u = __float_as_uint(f);
  unsigned rh = (u + 0x7FFFu + ((u >> 16) & 1u)) >> 16;
  float fh = __uint_as_float(rh << 16);
  float fl = f - fh;
  unsigned u2 = __float_as_uint(fl);
  unsigned rl = (u2 + 0x7FFFu + ((u2 >> 16) & 1u)) >> 16;
  hi = (short)rh; lo = (short)rl;
}

__device__ __forceinline__ unsigned short f2bf(float f) {
  unsigned u = __float_as_uint(f);
  return (unsigned short)((u + 0x7FFFu + ((u >> 16) & 1u)) >> 16);
}
__device__ __forceinline__ float bf2f(unsigned short h) {
  return __uint_as_float(((unsigned)h) << 16);
}

__device__ __forceinline__ void ld32(float* xr, const float* p) {
#pragma unroll
  for (int i = 0; i < 32; i += 4) {
    float4 v = F4(&p[i]);
    xr[i] = v.x; xr[i+1] = v.y; xr[i+2] = v.z; xr[i+3] = v.w;
  }
}

__device__ __forceinline__ float dot32r(const float* __restrict__ w, const float* xr) {
  float s = 0.f;
#pragma unroll
  for (int i = 0; i < 32; i += 4) {
    float4 ww = F4(&w[i]);
    s = fmaf(xr[i],   ww.x, s);
    s = fmaf(xr[i+1], ww.y, s);
    s = fmaf(xr[i+2], ww.z, s);
    s = fmaf(xr[i+3], ww.w, s);
  }
  return s;
}

// ---------------- embedding ----------------
__global__ __launch_bounds__(128) void embed_kernel(
    const float* __restrict__ xa, const float* __restrict__ W,
    const float* __restrict__ b, float* __restrict__ x)
{
  __shared__ float a[64];
  const int n = blockIdx.x, t = threadIdx.x;
  if (t < 64) a[t] = xa[n*64 + t];
  __syncthreads();
  float s = b[t];
#pragma unroll 8
  for (int f = 0; f < 64; ++f) s = fmaf(a[f], W[f*128 + t], s);
  x[n*128 + t] = s;
}

// ---------------- CSR build ----------------
__global__ __launch_bounds__(256) void hist_kernel(const int* __restrict__ ei, int* __restrict__ cnt) {
  const int e = blockIdx.x*256 + threadIdx.x;
  atomicAdd(&cnt[ei[NE + e]], 1);
}

__global__ __launch_bounds__(1024) void scan_kernel(
    const int* __restrict__ cnt, int* __restrict__ off, int* __restrict__ cur)
{
  __shared__ int wsum[16];
  const int t = threadIdx.x;
  int local[32];
  const int base = t*32;
  int s = 0;
#pragma unroll
  for (int i = 0; i < 32; ++i) { local[i] = cnt[base+i]; s += local[i]; }
  int pre = s;
  const int lane = t & 63;
#pragma unroll
  for (int o = 1; o < 64; o <<= 1) { int v = __shfl_up(pre, o); if (lane >= o) pre += v; }
  if (lane == 63) wsum[t >> 6] = pre;
  __syncthreads();
  if (t == 0) { int a = 0; for (int w = 0; w < 16; ++w) { int v = wsum[w]; wsum[w] = a; a += v; } }
  __syncthreads();
  int excl = wsum[t >> 6] + pre - s;
#pragma unroll
  for (int i = 0; i < 32; ++i) { off[base+i] = excl; cur[base+i] = excl; excl += local[i]; }
  if (t == 1023) off[NN] = excl;
}

__global__ __launch_bounds__(256) void scatter_kernel(
    const float* __restrict__ pos, const int* __restrict__ ei,
    int* __restrict__ cur, int* __restrict__ csr_src, float* __restrict__ csr_df)
{
  const int e = blockIdx.x*256 + threadIdx.x;
  const int s = ei[e];
  const int d = ei[NE + e];
  float dx = pos[d*3+0] - pos[s*3+0];
  float dy = pos[d*3+1] - pos[s*3+1];
  float dz = pos[d*3+2] - pos[s*3+2];
  float dist = sqrtf(dx*dx + dy*dy + dz*dz + 1e-12f);
  const int slot = atomicAdd(&cur[d], 1);
  csr_src[slot] = s;
  csr_df[slot*3+0] = dist;
  csr_df[slot*3+1] = 1.f/(1.f + dist);
  csr_df[slot*3+2] = expf(-dist);
}

// ---------------- weight prep (unchanged layout) ----------------
__device__ __forceinline__ void pack_decode(int r, int N, int &k, int &n) {
  const int j = r & 7, lane = (r >> 3) & 63, rest = r >> 9;
  const int NT = N >> 4;
  const int t = rest % NT, kc = rest / NT;
  k = kc*32 + (lane >> 4)*8 + j;
  n = t*16 + (lane & 15);
}

__global__ __launch_bounds__(256) void prep_kernel(
    const float* __restrict__ mp_W1, const float* __restrict__ mp_W2,
    const float* __restrict__ win, const float* __restrict__ wout,
    const float* __restrict__ mp_b1,
    short* __restrict__ bh, short* __restrict__ bl, float* __restrict__ pqbias)
{
  const int i = blockIdx.x*256 + threadIdx.x;
  if (i < 768) { const int l = i >> 8, t = i & 255; pqbias[i] = t < 128 ? mp_b1[l*128 + t] : 0.f; }
  if (i >= 212992) return;
  int k, n; float v;
  if (i < 98304) {
    const int l = i / 32768, r = i % 32768;
    pack_decode(r, 256, k, n);
    const float* W = mp_W1 + (size_t)l*259*128;
    v = (n < 128) ? W[k*128 + n] : W[(128+k)*128 + (n-128)];
  } else if (i < 147456) {
    const int q = i - 98304, l = q / 16384, r = q % 16384;
    pack_decode(r, 128, k, n);
    v = mp_W2[(size_t)l*16384 + k*128 + n];
  } else if (i < 196608) {
    const int r = i - 147456;
    pack_decode(r, 384, k, n);
    v = win[n*128 + k];
  } else {
    const int r = i - 196608;
    pack_decode(r, 128, k, n);
    v = wout[n*128 + k];
  }
  short h, lo; bf16split(v, h, lo);
  bh[i] = h; bl[i] = lo;
}

// ---------------- generic MFMA GEMM: C[M][·] = A[M][128] @ B + bias ----------------
// block = 4 waves; wave = 32 rows x 64 cols; grid = (M/128, ncols/64). split-bf16 3-term.
// If qbf != null, columns >= 128 are written as bf16 to qbf[row*128 + col-128] instead of C.
__global__ __launch_bounds__(256, 2) void mfma_gemm_kernel(
    const float* __restrict__ A, int lda,
    const short* __restrict__ Bh, const short* __restrict__ Bl,
    const float* __restrict__ bias, float* __restrict__ C, int ncols, int ldc,
    unsigned short* __restrict__ qbf)
{
  const int lane = threadIdx.x & 63, wid = threadIdx.x >> 6;
  const int m0 = blockIdx.x * 128 + wid * 32;
  const int n0 = blockIdx.y * 64;
  const int NT = ncols >> 4;
  const int cl = lane & 15, kg = lane >> 4;

  bf16x8 Ah[2][4], Al[2][4];
#pragma unroll
  for (int s = 0; s < 2; ++s)
#pragma unroll
    for (int kc = 0; kc < 4; ++kc) {
      const float* ap = &A[(size_t)(m0 + s*16 + cl)*lda + kc*32 + kg*8];
      const float4 f0 = F4(ap), f1 = F4(ap + 4);
      const float fv[8] = {f0.x,f0.y,f0.z,f0.w,f1.x,f1.y,f1.z,f1.w};
      union { short s[8]; bf16x8 b; } uh, ul;
#pragma unroll
      for (int j = 0; j < 8; ++j) bf16split(fv[j], uh.s[j], ul.s[j]);
      Ah[s][kc] = uh.b; Al[s][kc] = ul.b;
    }

  f32x4 acc[2][4];
#pragma unroll
  for (int s = 0; s < 2; ++s)
#pragma unroll
    for (int t = 0; t < 4; ++t) acc[s][t] = (f32x4){0.f,0.f,0.f,0.f};

#pragma unroll
  for (int kc = 0; kc < 4; ++kc) {
    bf16x8 Bfh[4], Bfl[4];
#pragma unroll
    for (int t = 0; t < 4; ++t) {
      const size_t off = (((size_t)(kc*NT + (n0 >> 4) + t))*64 + lane)*8;
      Bfh[t] = *(const bf16x8*)&Bh[off];
      Bfl[t] = *(const bf16x8*)&Bl[off];
    }
#pragma unroll
    for (int s = 0; s < 2; ++s)
#pragma unroll
      for (int t = 0; t < 4; ++t)
        acc[s][t] = __builtin_amdgcn_mfma_f32_16x16x32_bf16(Ah[s][kc], Bfh[t], acc[s][t], 0, 0, 0);
#pragma unroll
    for (int s = 0; s < 2; ++s)
#pragma unroll
      for (int t = 0; t < 4; ++t)
        acc[s][t] = __builtin_amdgcn_mfma_f32_16x16x32_bf16(Ah[s][kc], Bfl[t], acc[s][t], 0, 0, 0);
#pragma unroll
    for (int s = 0; s < 2; ++s)
#pragma unroll
      for (int t = 0; t < 4; ++t)
        acc[s][t] = __builtin_amdgcn_mfma_f32_16x16x32_bf16(Al[s][kc], Bfh[t], acc[s][t], 0, 0, 0);
  }

#pragma unroll
  for (int t = 0; t < 4; ++t) {
    const int col = n0 + t*16 + cl;
    const float bv = bias[col];
#pragma unroll
    for (int s = 0; s < 2; ++s) {
      const int rbase = m0 + s*16 + kg*4;
#pragma unroll
      for (int r = 0; r < 4; ++r) {
        const float v = acc[s][t][r] + bv;
        if (qbf && col >= 128)
          qbf[(size_t)(rbase + r)*128 + (col - 128)] = f2bf(v);
        else
          C[(size_t)(rbase + r)*ldc + col] = v;
      }
    }
  }
}

// ---------------- MFMA GEMM + residual + LN ----------------
__global__ __launch_bounds__(256, 2) void mfma_gemm_ln_kernel(
    const float* __restrict__ A, int lda,
    const short* __restrict__ Bh, const short* __restrict__ Bl,
    const float* __restrict__ b2, const int* __restrict__ csr_off,
    const float* __restrict__ g, const float* __restrict__ bb,
    float* __restrict__ x)
{
  const int lane = threadIdx.x & 63, wid = threadIdx.x >> 6;
  const int m0 = blockIdx.x * 64 + wid * 16;
  const int cl = lane & 15, kg = lane >> 4;

  bf16x8 Ah[4], Al[4];
#pragma unroll
  for (int kc = 0; kc < 4; ++kc) {
    const float* ap = &A[(size_t)(m0 + cl)*lda + kc*32 + kg*8];
    const float4 f0 = F4(ap), f1 = F4(ap + 4);
    const float fv[8] = {f0.x,f0.y,f0.z,f0.w,f1.x,f1.y,f1.z,f1.w};
    union { short s[8]; bf16x8 b; } uh, ul;
#pragma unroll
    for (int j = 0; j < 8; ++j) bf16split(fv[j], uh.s[j], ul.s[j]);
    Ah[kc] = uh.b; Al[kc] = ul.b;
  }

  f32x4 acc[8];
#pragma unroll
  for (int t = 0; t < 8; ++t) acc[t] = (f32x4){0.f,0.f,0.f,0.f};

#pragma unroll
  for (int kc = 0; kc < 4; ++kc) {
    bf16x8 Bfh[8], Bfl[8];
#pragma unroll
    for (int t = 0; t < 8; ++t) {
      const size_t off = (((size_t)(kc*8 + t))*64 + lane)*8;
      Bfh[t] = *(const bf16x8*)&Bh[off];
      Bfl[t] = *(const bf16x8*)&Bl[off];
    }
#pragma unroll
    for (int t = 0; t < 8; ++t)
      acc[t] = __builtin_amdgcn_mfma_f32_16x16x32_bf16(Ah[kc], Bfh[t], acc[t], 0, 0, 0);
#pragma unroll
    for (int t = 0; t < 8; ++t)
      acc[t] = __builtin_amdgcn_mfma_f32_16x16x32_bf16(Ah[kc], Bfl[t], acc[t], 0, 0, 0);
#pragma unroll
    for (int t = 0; t < 8; ++t)
      acc[t] = __builtin_amdgcn_mfma_f32_16x16x32_bf16(Al[kc], Bfh[t], acc[t], 0, 0, 0);
  }

  const int r0 = m0 + kg*4;
  float sflag[4];
#pragma unroll
  for (int r = 0; r < 4; ++r)
    sflag[r] = (csr_off[r0 + r + 1] > csr_off[r0 + r]) ? 1.f : 0.f;

  float ps[4] = {0.f,0.f,0.f,0.f}, pq[4] = {0.f,0.f,0.f,0.f};
  float yv[8][4];
#pragma unroll
  for (int t = 0; t < 8; ++t) {
    const int col = t*16 + cl;
    const float b2v = b2[col];
#pragma unroll
    for (int r = 0; r < 4; ++r) {
      const float y = acc[t][r] + sflag[r]*b2v + x[(size_t)(r0 + r)*128 + col];
      yv[t][r] = y;
      ps[r] += y;
      pq[r] = fmaf(y, y, pq[r]);
    }
  }
#pragma unroll
  for (int o = 1; o < 16; o <<= 1) {
#pragma unroll
    for (int r = 0; r < 4; ++r) { ps[r] += __shfl_xor(ps[r], o); pq[r] += __shfl_xor(pq[r], o); }
  }
#pragma unroll
  for (int r = 0; r < 4; ++r) {
    const float mu = ps[r] * (1.f/128.f);
    const float var = pq[r]*(1.f/128.f) - mu*mu;
    const float rstd = rsqrtf(var + 1e-5f);
#pragma unroll
    for (int t = 0; t < 8; ++t) {
      const int col = t*16 + cl;
      x[(size_t)(r0 + r)*128 + col] = (yv[t][r] - mu)*rstd*g[col] + bb[col];
    }
  }
}

// ---------------- aggregation: P[n] <- mean_e relu(P[n]+Qbf[src]+df@W1c) ----------------
// 4 nodes/block, wave per node. Q gathered as bf16 (ushort2/lane); 8-edge load batches.
__global__ __launch_bounds__(256, 6) void agg_kernel(
    float* __restrict__ P, const unsigned short* __restrict__ Qbf,
    const int* __restrict__ csr_off, const int* __restrict__ csr_src,
    const float* __restrict__ csr_df, const float* __restrict__ W1)
{
  const int tid = threadIdx.x;
  const int node = blockIdx.x*4 + (tid >> 6);
  const int lane = tid & 63;
  const int c0 = lane*2;
  const int off0 = csr_off[node], off1 = csr_off[node+1];

  const float* __restrict__ w1c = W1 + 256*128;
  const float w00 = w1c[c0],       w01 = w1c[c0+1];
  const float w10 = w1c[128+c0],   w11 = w1c[128+c0+1];
  const float w20 = w1c[256+c0],   w21 = w1c[256+c0+1];
  const float2 p = *(const float2*)&P[(size_t)node*128 + c0];

  float a0 = 0.f, a1 = 0.f;
  int e = off0;
  for (; e + 8 <= off1; e += 8) {
    int sr[8];
#pragma unroll
    for (int j = 0; j < 8; ++j) sr[j] = csr_src[e+j];
    ushort2 qv[8];
#pragma unroll
    for (int j = 0; j < 8; ++j) qv[j] = *(const ushort2*)&Qbf[(size_t)sr[j]*128 + c0];
    float dfv[8][3];
#pragma unroll
    for (int j = 0; j < 8; ++j) {
      dfv[j][0] = csr_df[(e+j)*3+0];
      dfv[j][1] = csr_df[(e+j)*3+1];
      dfv[j][2] = csr_df[(e+j)*3+2];
    }
#pragma unroll
    for (int j = 0; j < 8; ++j) {
      float h0 = p.x + bf2f(qv[j].x);
      h0 = fmaf(dfv[j][0], w00, h0); h0 = fmaf(dfv[j][1], w10, h0); h0 = fmaf(dfv[j][2], w20, h0);
      float h1 = p.y + bf2f(qv[j].y);
      h1 = fmaf(dfv[j][0], w01, h1); h1 = fmaf(dfv[j][1], w11, h1); h1 = fmaf(dfv[j][2], w21, h1);
      a0 += fmaxf(h0, 0.f);
      a1 += fmaxf(h1, 0.f);
    }
  }
  for (; e < off1; ++e) {
    const ushort2 qv = *(const ushort2*)&Qbf[(size_t)csr_src[e]*128 + c0];
    const float d0 = csr_df[e*3+0], d1 = csr_df[e*3+1], d2 = csr_df[e*3+2];
    float h0 = p.x + bf2f(qv.x);
    h0 = fmaf(d0, w00, h0); h0 = fmaf(d1, w10, h0); h0 = fmaf(d2, w20, h0);
    float h1 = p.y + bf2f(qv.y);
    h1 = fmaf(d0, w01, h1); h1 = fmaf(d1, w11, h1); h1 = fmaf(d2, w21, h1);
    a0 += fmaxf(h0, 0.f);
    a1 += fmaxf(h1, 0.f);
  }
  const int deg = off1 - off0;
  const float rc = deg > 0 ? 1.f/(float)deg : 1.f;
  *(float2*)&P[(size_t)node*128 + c0] = make_float2(a0*rc, a1*rc);
}

// ---------------- per-molecule attention on dqkv[n][384]; O -> dv slot ----------------
__global__ __launch_bounds__(128) void attn_kernel(float* __restrict__ dqkv)
{
  __shared__ float sk[32*132];
  __shared__ float sv[32*132];
  const int tid = threadIdx.x;
  const int b = blockIdx.x;

  for (int idx = tid; idx < 1024; idx += 128) {
    const int a = idx >> 5, c4 = idx & 31;
    *(float4*)&sk[a*132 + c4*4] = F4(&dqkv[(size_t)(b*32+a)*384 + 128 + c4*4]);
    *(float4*)&sv[a*132 + c4*4] = F4(&dqkv[(size_t)(b*32+a)*384 + 256 + c4*4]);
  }
  __syncthreads();

  const int h = tid >> 5, qr = tid & 31;
  float qreg[32];
  ld32(qreg, &dqkv[(size_t)(b*32+qr)*384 + h*32]);

  float sc[32];
#pragma unroll
  for (int k = 0; k < 32; ++k)
    sc[k] = dot32r(&sk[k*132 + h*32], qreg) * 0.17677669529663687f;
  float mx = sc[0];
#pragma unroll
  for (int k = 1; k < 32; ++k) mx = fmaxf(mx, sc[k]);
  float se = 0.f;
#pragma unroll
  for (int k = 0; k < 32; ++k) { sc[k] = expf(sc[k] - mx); se += sc[k]; }
  const float inv = 1.f / se;

  __syncthreads();

  float od[32];
#pragma unroll
  for (int i = 0; i < 32; ++i) od[i] = 0.f;
#pragma unroll 4
  for (int k = 0; k < 32; ++k) {
    const float w = sc[k] * inv;
    const float* vr = &sv[k*132 + h*32];
#pragma unroll
    for (int i = 0; i < 32; i += 4) {
      float4 v = F4(&vr[i]);
      od[i]   = fmaf(w, v.x, od[i]);
      od[i+1] = fmaf(w, v.y, od[i+1]);
      od[i+2] = fmaf(w, v.z, od[i+2]);
      od[i+3] = fmaf(w, v.w, od[i+3]);
    }
  }
#pragma unroll
  for (int i = 0; i < 32; i += 4)
    *(float4*)&sk[qr*132 + h*32 + i] = make_float4(od[i], od[i+1], od[i+2], od[i+3]);
  __syncthreads();

  for (int idx = tid; idx < 1024; idx += 128) {
    const int a = idx >> 5, c4 = idx & 31;
    *(float4*)&dqkv[(size_t)(b*32+a)*384 + 256 + c4*4] = F4(&sk[a*132 + c4*4]);
  }
}

// ---------------- per-molecule pooling + proj ----------------
__global__ __launch_bounds__(128) void pool_kernel(
    const float* __restrict__ att, const float* __restrict__ x,
    const float* __restrict__ pW, const float* __restrict__ pb,
    float* __restrict__ expl, float* __restrict__ lrn)
{
  __shared__ float satt[32*132];
  __shared__ float sx[32*132];
  __shared__ float aw_l[32];
  __shared__ float spool[512];
  const int tid = threadIdx.x;
  const int b = blockIdx.x;

  for (int idx = tid; idx < 1024; idx += 128) {
    const int a = idx >> 5, c4 = idx & 31;
    *(float4*)&satt[a*132 + c4*4] = F4(&att[(size_t)(b*32+a)*128 + c4*4]);
    *(float4*)&sx[a*132 + c4*4]   = F4(&x[(size_t)(b*32+a)*128 + c4*4]);
  }
  __syncthreads();

  {
    const int a = tid >> 2, q4 = tid & 3;
    float sp = 0.f;
#pragma unroll
    for (int i = 0; i < 32; ++i)
      sp = fmaf(satt[a*132 + q4*32 + i], sx[a*132 + q4*32 + i], sp);
    sp += __shfl_xor(sp, 1);
    sp += __shfl_xor(sp, 2);
    if (q4 == 0) aw_l[a] = sp;
  }
  __syncthreads();

  {
    float awr[32];
    float mxl = aw_l[0];
#pragma unroll
    for (int a = 1; a < 32; ++a) mxl = fmaxf(mxl, aw_l[a]);
    float se = 0.f;
#pragma unroll
    for (int a = 0; a < 32; ++a) { awr[a] = expf(aw_l[a] - mxl); se += awr[a]; }
    const float inv = 1.f / se;
    const int c = tid;
    float mx = -3.4e38f, sm = 0.f, wm = 0.f, ex = 0.f;
#pragma unroll
    for (int a = 0; a < 32; ++a) {
      const float v = satt[a*132 + c];
      mx = fmaxf(mx, v);
      sm += v;
      wm = fmaf(v, awr[a], wm);
      ex += sx[a*132 + c];
    }
    wm *= inv;
    const float mean = sm * 0.03125f;
    float s2 = 0.f;
#pragma unroll
    for (int a = 0; a < 32; ++a) {
      const float d = satt[a*132 + c] - mean;
      s2 = fmaf(d, d, s2);
    }
    const float stdp = sqrtf(s2 * (1.f/31.f));  // ddof=1
    expl[b*128 + c] = ex * 0.03125f;
    spool[c]       = wm;
    spool[128 + c] = mx;
    spool[256 + c] = mean;
    spool[384 + c] = stdp;
  }
  __syncthreads();

  if (tid < 64) {
    const int k = tid >> 4, qq = tid & 15;
    const float* pk = pW + k*2048;
    float s0 = 0.f, s1 = 0.f, s2 = 0.f, s3 = 0.f;
    for (int h2 = 0; h2 < 128; h2 += 4) {
      s0 = fmaf(spool[k*128 + h2],   pk[h2*16 + qq],     s0);
      s1 = fmaf(spool[k*128 + h2+1], pk[(h2+1)*16 + qq], s1);
      s2 = fmaf(spool[k*128 + h2+2], pk[(h2+2)*16 + qq], s2);
      s3 = fmaf(spool[k*128 + h2+3], pk[(h2+3)*16 + qq], s3);
    }
    lrn[b*64 + tid] = pb[k*16 + qq] + (s0+s1) + (s2+s3);
  }
}

// ---------------- per-(property, molecule) gated MLP heads (4-way split accumulators) ----------------
__global__ __launch_bounds__(64) void head_kernel(
    const float* __restrict__ molf, const float* __restrict__ lrn,
    const float* __restrict__ expl,
    const float* __restrict__ mol_gate, const float* __restrict__ lrn_gate,
    const float* __restrict__ meW1, const float* __restrict__ meb1,
    const float* __restrict__ meW2, const float* __restrict__ meb2,
    const float* __restrict__ leW1, const float* __restrict__ leb1,
    const float* __restrict__ leW2, const float* __restrict__ leb2,
    const float* __restrict__ fW1, const float* __restrict__ fb1,
    const float* __restrict__ fW2, const float* __restrict__ fb2,
    const float* __restrict__ hW1, const float* __restrict__ hb1,
    const float* __restrict__ hW2, const float* __restrict__ hb2,
    float* __restrict__ out)
{
  const int b = blockIdx.x, p = blockIdx.y, t = threadIdx.x;
  __shared__ float sgm[200];
  __shared__ float sgl[64];
  __shared__ float sA[64];
  __shared__ float sB[64];
  __shared__ float scomb[256];
  __shared__ float sf1[128];
  __shared__ float sf2[64];

  for (int m = t; m < 200; m += 64)
    sgm[m] = molf[b*200 + m] * sigmoidf_(mol_gate[p*200 + m]);
  sgl[t] = lrn[b*64 + t] * sigmoidf_(lrn_gate[p*64 + t]);
  scomb[t]      = expl[b*128 + t];
  scomb[64 + t] = expl[b*128 + 64 + t];
  __syncthreads();

  { // molemb1 (K=200) + lrnemb1 (K=64), 4-way chains
    const float* w = meW1 + p*12800;
    float a0=0.f,a1=0.f,a2=0.f,a3=0.f;
    for (int m = 0; m < 200; m += 4) {
      a0 = fmaf(sgm[m],   w[m*64 + t],       a0);
      a1 = fmaf(sgm[m+1], w[(m+1)*64 + t],   a1);
      a2 = fmaf(sgm[m+2], w[(m+2)*64 + t],   a2);
      a3 = fmaf(sgm[m+3], w[(m+3)*64 + t],   a3);
    }
    sA[t] = fmaxf(meb1[p*64 + t] + (a0+a1) + (a2+a3), 0.f);
    const float* w2 = leW1 + p*4096;
    float b0=0.f,b1_=0.f,b2_=0.f,b3=0.f;
    for (int m = 0; m < 64; m += 4) {
      b0  = fmaf(sgl[m],   w2[m*64 + t],     b0);
      b1_ = fmaf(sgl[m+1], w2[(m+1)*64 + t], b1_);
      b2_ = fmaf(sgl[m+2], w2[(m+2)*64 + t], b2_);
      b3  = fmaf(sgl[m+3], w2[(m+3)*64 + t], b3);
    }
    sB[t] = fmaxf(leb1[p*64 + t] + (b0+b1_) + (b2_+b3), 0.f);
  }
  __syncthreads();
  { // molemb2 + lrnemb2 (K=64)
    const float* w = meW2 + p*4096;
    float a0=0.f,a1=0.f,a2=0.f,a3=0.f;
    for (int h = 0; h < 64; h += 4) {
      a0 = fmaf(sA[h],   w[h*64 + t],       a0);
      a1 = fmaf(sA[h+1], w[(h+1)*64 + t],   a1);
      a2 = fmaf(sA[h+2], w[(h+2)*64 + t],   a2);
      a3 = fmaf(sA[h+3], w[(h+3)*64 + t],   a3);
    }
    scomb[128 + t] = meb2[p*64 + t] + (a0+a1) + (a2+a3);
    const float* w2 = leW2 + p*4096;
    float b0=0.f,b1_=0.f,b2_=0.f,b3=0.f;
    for (int h = 0; h < 64; h += 4) {
      b0  = fmaf(sB[h],   w2[h*64 + t],     b0);
      b1_ = fmaf(sB[h+1], w2[(h+1)*64 + t], b1_);
      b2_ = fmaf(sB[h+2], w2[(h+2)*64 + t], b2_);
      b3  = fmaf(sB[h+3], w2[(h+3)*64 + t], b3);
    }
    scomb[192 + t] = leb2[p*64 + t] + (b0+b1_) + (b2_+b3);
  }
  __syncthreads();
  { // fus1 (K=256, 2 outputs), 4-way chains each
    const float* w = fW1 + p*32768;
    float s00=0.f,s01=0.f,s02=0.f,s03=0.f;
    float s10=0.f,s11=0.f,s12=0.f,s13=0.f;
    for (int c = 0; c < 256; c += 4) {
      const float v0 = scomb[c], v1 = scomb[c+1], v2 = scomb[c+2], v3 = scomb[c+3];
      s00 = fmaf(v0, w[c*128 + t],          s00);
      s01 = fmaf(v1, w[(c+1)*128 + t],      s01);
      s02 = fmaf(v2, w[(c+2)*128 + t],      s02);
      s03 = fmaf(v3, w[(c+3)*128 + t],      s03);
      s10 = fmaf(v0, w[c*128 + 64 + t],     s10);
      s11 = fmaf(v1, w[(c+1)*128 + 64 + t], s11);
      s12 = fmaf(v2, w[(c+2)*128 + 64 + t], s12);
      s13 = fmaf(v3, w[(c+3)*128 + 64 + t], s13);
    }
    sf1[t]      = fmaxf(fb1[p*128 + t]      + (s00+s01) + (s02+s03), 0.f);
    sf1[64 + t] = fmaxf(fb1[p*128 + 64 + t] + (s10+s11) + (s12+s13), 0.f);
  }
  __syncthreads();
  { // fus2 (K=128)
    const float* w = fW2 + p*8192;
    float a0=0.f,a1=0.f,a2=0.f,a3=0.f;
    for (int h = 0; h < 128; h += 4) {
      a0 = fmaf(sf1[h],   w[h*64 + t],       a0);
      a1 = fmaf(sf1[h+1], w[(h+1)*64 + t],   a1);
      a2 = fmaf(sf1[h+2], w[(h+2)*64 + t],   a2);
      a3 = fmaf(sf1[h+3], w[(h+3)*64 + t],   a3);
    }
    sf2[t] = fb2[p*64 + t] + (a0+a1) + (a2+a3);
  }
  __syncthreads();
  float val = 0.f;
  if (t < 32) { // head1 (K=64) * hW2
    const float* w = hW1 + p*2048;
    float a0=0.f,a1=0.f,a2=0.f,a3=0.f;
    for (int h = 0; h < 64; h += 4) {
      a0 = fmaf(sf2[h],   w[h*32 + t],       a0);
      a1 = fmaf(sf2[h+1], w[(h+1)*32 + t],   a1);
      a2 = fmaf(sf2[h+2], w[(h+2)*32 + t],   a2);
      a3 = fmaf(sf2[h+3], w[(h+3)*32 + t],   a3);
    }
    val = fmaxf(hb1[p*32 + t] + (a0+a1) + (a2+a3), 0.f) * hW2[p*32 + t];
  }
#pragma unroll
  for (int o = 1; o < 32; o <<= 1) val += __shfl_xor(val, o);
  if (t == 0) out[p*1024 + b] = val + hb2[p];
}

extern "C" void kernel_launch(void* const* d_in, const int* in_sizes, int n_in,
                              void* d_out, int out_size, void* d_ws, size_t ws_size,
                              hipStream_t stream) {
  const float* x_atoms    = (const float*)d_in[0];
  const float* pos        = (const float*)d_in[1];
  const float* molf       = (const float*)d_in[3];
  const float* emb_W      = (const float*)d_in[4];
  const float* emb_b      = (const float*)d_in[5];
  const float* mp_W1      = (const float*)d_in[6];
  const float* mp_b1      = (const float*)d_in[7];
  const float* mp_W2      = (const float*)d_in[8];
  const float* mp_b2      = (const float*)d_in[9];
  const float* ln_g       = (const float*)d_in[10];
  const float* ln_b       = (const float*)d_in[11];
  const float* attn_in_w  = (const float*)d_in[12];
  const float* attn_in_b  = (const float*)d_in[13];
  const float* attn_out_w = (const float*)d_in[14];
  const float* attn_out_b = (const float*)d_in[15];
  const float* pool_W     = (const float*)d_in[16];
  const float* pool_b     = (const float*)d_in[17];
  const float* mol_gate   = (const float*)d_in[18];
  const float* lrn_gate   = (const float*)d_in[19];
  const float* meW1       = (const float*)d_in[20];
  const float* meb1       = (const float*)d_in[21];
  const float* meW2       = (const float*)d_in[22];
  const float* meb2       = (const float*)d_in[23];
  const float* leW1       = (const float*)d_in[24];
  const float* leb1       = (const float*)d_in[25];
  const float* leW2       = (const float*)d_in[26];
  const float* leb2       = (const float*)d_in[27];
  const float* fW1        = (const float*)d_in[28];
  const float* fb1        = (const float*)d_in[29];
  const float* fW2        = (const float*)d_in[30];
  const float* fb2        = (const float*)d_in[31];
  const float* hW1        = (const float*)d_in[32];
  const float* hb1        = (const float*)d_in[33];
  const float* hW2        = (const float*)d_in[34];
  const float* hb2        = (const float*)d_in[35];
  const int*   ei         = (const int*)d_in[36];

  float* ws      = (float*)d_ws;
  float* x       = ws;                              // NN*128
  float* region  = x + (size_t)NN*128;              // NN*384 floats
  float* P       = region;                          // NN*128 fp32
  unsigned short* Qbf = (unsigned short*)(region + (size_t)NN*128); // NN*128 bf16
  float* dqkv    = region;                          // NN*384 (overlays P/Qbf after layers)
  float* att     = region + (size_t)NN*384;         // NN*128
  float* csr_df  = att + (size_t)NN*128;            // NE*3
  int*   csr_src = (int*)(csr_df + (size_t)NE*3);   // NE
  int*   cnt_i   = csr_src + NE;                    // NN
  int*   csr_off = cnt_i + NN;                      // NN+1
  int*   cur     = csr_off + NN + 1;                // NN
  float* lrn     = (float*)(cur + NN);              // NB*64
  float* expl    = lrn + NB*64;                     // NB*128
  float* pqbias  = expl + NB*128;                   // 3*256
  short* bh      = (short*)(pqbias + 768);          // 212992 shorts
  short* bl      = bh + 212992;                     // 212992 shorts

  const int W1AB_OFF = 0;        // + l*32768, N=256
  const int W2_OFF   = 98304;    // + l*16384, N=128
  const int WIN_OFF  = 147456;   // N=384
  const int WOUT_OFF = 196608;   // N=128

  hipMemsetAsync(cnt_i, 0, (size_t)NN*sizeof(int), stream);

  embed_kernel<<<NN, 128, 0, stream>>>(x_atoms, emb_W, emb_b, x);
  hist_kernel<<<NE/256, 256, 0, stream>>>(ei, cnt_i);
  scan_kernel<<<1, 1024, 0, stream>>>(cnt_i, csr_off, cur);
  scatter_kernel<<<NE/256, 256, 0, stream>>>(pos, ei, cur, csr_src, csr_df);
  prep_kernel<<<(212992 + 255)/256, 256, 0, stream>>>(mp_W1, mp_W2, attn_in_w, attn_out_w,
                                                      mp_b1, bh, bl, pqbias);

  for (int l = 0; l < 3; ++l) {
    mfma_gemm_kernel<<<dim3(NN/128, 4), 256, 0, stream>>>(
        x, 128, bh + W1AB_OFF + l*32768, bl + W1AB_OFF + l*32768,
        pqbias + l*256, P, 256, 128, Qbf);
    agg_kernel<<<NN/4, 256, 0, stream>>>(P, Qbf, csr_off, csr_src, csr_df,
                                         mp_W1 + (size_t)l*259*128);
    mfma_gemm_ln_kernel<<<NN/64, 256, 0, stream>>>(
        P, 128, bh + W2_OFF + l*16384, bl + W2_OFF + l*16384,
        mp_b2 + l*128, csr_off, ln_g + l*128, ln_b + l*128, x);
  }

  mfma_gemm_kernel<<<dim3(NN/128, 6), 256, 0, stream>>>(
      x, 128, bh + WIN_OFF, bl + WIN_OFF, attn_in_b, dqkv, 384, 384, nullptr);
  attn_kernel<<<NB, 128, 0, stream>>>(dqkv);
  mfma_gemm_kernel<<<dim3(NN/128, 2), 256, 0, stream>>>(
      dqkv + 256, 384, bh + WOUT_OFF, bl + WOUT_OFF, attn_out_b, att, 128, 128, nullptr);
  pool_kernel<<<NB, 128, 0, stream>>>(att, x, pool_W, pool_b, expl, lrn);
  head_kernel<<<dim3(NB, 4), 64, 0, stream>>>(molf, lrn, expl, mol_gate, lrn_gate,
      meW1, meb1, meW2, meb2, leW1, leb1, leW2, leb2,
      fW1, fb1, fW2, fb2, hW1, hb1, hW2, hb2, (float*)d_out);
}